// Round 9
// baseline (1737.206 us; speedup 1.0000x reference)
//
#include <hip/hip_runtime.h>
#include <cstdint>
#include <cstddef>

// ---------------------------------------------------------------------------
// Show-Attend-Tell decoder on MI355X (round 8 = round 7 + prep grid fix).
// 2 launches per decode step:
//   KA att_awe_k: in-block att2 & gate matvecs ([k][n] coalesced weights)
//                 + e/relu/softmax + awe
//   KB gates_lstm_k: gates GEMM K=2560 (pipelined k-loop) + fused LSTM
// Precompute (5 launches): conv_mean, prep_k (transposes + casts + embg),
// h0c0 GEMM, att1 GEMM (XCD-chunked), eprec GEMM. y deferred to one GEMM.
// NOTES:
//  - round-3 post-mortem: persistent coop kernel w/ agent-scope acquire-spin
//    grid barrier = ~125us/barrier + cache-invalidate storms. Do NOT revisit.
//  - round-4 post-mortem: inter-launch gap ~7-10us -> minimize launch count.
//  - round-6 post-mortem: matvec with [n][k] weights = 64 cache lines per
//    wave load (uncoalesced), +45us/step. Matvec weights MUST be [k][n].
//  - round-7 post-mortem: prep_k grid must cover embg section: 15520+4864
//    blocks. Section boundaries are ABSOLUTE block ids - grid = 20384.
// ---------------------------------------------------------------------------

#define DEV __device__ __forceinline__

typedef __attribute__((ext_vector_type(8))) short s16x8;
typedef __attribute__((ext_vector_type(4))) float f32x4;

constexpr int Bb = 128, Pp = 196, Dd = 2048, Aa = 512, Ee = 512, Hh = 512, Vv = 10000;
constexpr int Tt = 19, TMAX = 20;
constexpr int KXN = 2560;             // xin = [awe(2048), h(512)]
constexpr int NVP = 10048;

DEV float fbs(short s) {
    union { uint32_t u; float f; } v;
    v.u = ((uint32_t)(uint16_t)s) << 16;
    return v.f;
}
DEV short bfs(float f) {
    union { float f; uint32_t u; } v;
    v.f = f;
    uint32_t u = v.u;
    uint32_t r = (u + 0x7FFFu + ((u >> 16) & 1u)) >> 16;  // RNE
    return (short)(uint16_t)r;
}
DEV void upk(uint32_t v, float& lo, float& hi) {
    union { uint32_t u; float f; } a, b;
    a.u = v << 16;
    b.u = v & 0xffff0000u;
    lo = a.f;
    hi = b.f;
}

// ---------------------------------------------------------------------------
// Standalone GEMM (precompute + y). B stored [N][K]. LDS XOR-swizzled.
// EPI: 0 = bf16 out + bias, XCD-chunked 1-D grid (att1; 392 blocks)
//      1 = bf16 out, no bias (eprec)
//      3 = deferred y with mask (1-D XCD-chunked grid 157*19)
//      6 = h0c0: n<512 -> xin h-slot bf16 (+h_fc_b); else c_state (+c_fc_b)
// ---------------------------------------------------------------------------
template<int BM, int BN, int BK, int TH, int WR, int WC, int EPI>
__global__ __launch_bounds__(TH) void gemm_k(
    const short* __restrict__ Ag, int lda,
    const short* __restrict__ Bg, int ldb,
    int K,
    float* __restrict__ outF, float* __restrict__ outF2,
    short* __restrict__ outH, short* __restrict__ outH2,
    int ldo,
    const float* __restrict__ bias, const float* __restrict__ bias2,
    const int* __restrict__ lens)
{
    constexpr int NCH = BK / 8;
    constexpr int AU = NCH * BM, BU = NCH * BN;
    constexpr int APT = AU / TH, BPT = BU / TH;
    constexpr int WM = BM / WR, WN = BN / WC;
    constexpr int FM = WM / 16, FN = WN / 16;

    __shared__ __align__(16) short sA[AU * 8];
    __shared__ __align__(16) short sB[BU * 8];

    const int tid = threadIdx.x, lane = tid & 63, wid = tid >> 6;
    const int l15 = lane & 15, l4 = lane >> 4;

    int m0, n0, trow_ = 0;
    if constexpr (EPI == 0) {
        int task = (blockIdx.x & 7) * 49 + (blockIdx.x >> 3);   // 392 blocks
        m0 = (task >> 1) * BM;
        n0 = (task & 1) * BN;
    } else if constexpr (EPI == 3) {
        const int nwg = (int)gridDim.x;                         // 157*19
        const int qq = nwg >> 3, rr = nwg & 7;
        int xcd = (int)blockIdx.x & 7, idx = (int)blockIdx.x >> 3;
        int task = (xcd < rr) ? xcd * (qq + 1) + idx
                              : rr * (qq + 1) + (xcd - rr) * qq + idx;
        int npanel = task / Tt;
        trow_ = task - npanel * Tt;
        m0 = trow_ * BM;
        n0 = npanel * BN;
    } else {
        m0 = blockIdx.y * BM;
        n0 = blockIdx.x * BN;
    }
    const int wr = wid / WC, wc = wid % WC;

    f32x4 acc[FM][FN];
    #pragma unroll
    for (int i = 0; i < FM; ++i)
        #pragma unroll
        for (int j = 0; j < FN; ++j) acc[i][j] = {0.f, 0.f, 0.f, 0.f};

    for (int kt = 0; kt < K; kt += BK) {
        s16x8 ra[APT], rb[BPT];
        #pragma unroll
        for (int i = 0; i < APT; ++i) {
            int q2 = tid + TH * i;
            int r2 = q2 / NCH, ch = q2 % NCH;
            ra[i] = *(const s16x8*)(Ag + (size_t)(m0 + r2) * lda + kt + ch * 8);
        }
        #pragma unroll
        for (int i = 0; i < BPT; ++i) {
            int q2 = tid + TH * i;
            int r2 = q2 / NCH, ch = q2 % NCH;
            rb[i] = *(const s16x8*)(Bg + (size_t)(n0 + r2) * ldb + kt + ch * 8);
        }
        __syncthreads();
        #pragma unroll
        for (int i = 0; i < APT; ++i) {
            int q2 = tid + TH * i;
            int r2 = q2 / NCH, ch = q2 % NCH;
            *(s16x8*)(sA + (r2 * NCH + (ch ^ (r2 & 7))) * 8) = ra[i];
        }
        #pragma unroll
        for (int i = 0; i < BPT; ++i) {
            int q2 = tid + TH * i;
            int r2 = q2 / NCH, ch = q2 % NCH;
            *(s16x8*)(sB + (r2 * NCH + (ch ^ (r2 & 7))) * 8) = rb[i];
        }
        __syncthreads();
        #pragma unroll
        for (int ks = 0; ks < BK / 32; ++ks) {
            s16x8 af[FM], bf[FN];
            #pragma unroll
            for (int fm = 0; fm < FM; ++fm) {
                int rr2 = wr * WM + fm * 16 + l15, cc = ks * 4 + l4;
                af[fm] = *(const s16x8*)&sA[(rr2 * NCH + (cc ^ (rr2 & 7))) * 8];
            }
            #pragma unroll
            for (int fn = 0; fn < FN; ++fn) {
                int rr2 = wc * WN + fn * 16 + l15, cc = ks * 4 + l4;
                bf[fn] = *(const s16x8*)&sB[(rr2 * NCH + (cc ^ (rr2 & 7))) * 8];
            }
            #pragma unroll
            for (int fm = 0; fm < FM; ++fm)
                #pragma unroll
                for (int fn = 0; fn < FN; ++fn)
                    acc[fm][fn] = __builtin_amdgcn_mfma_f32_16x16x32_bf16(af[fm], bf[fn], acc[fm][fn], 0, 0, 0);
        }
        __syncthreads();
    }

    #pragma unroll
    for (int fm = 0; fm < FM; ++fm)
        #pragma unroll
        for (int fn = 0; fn < FN; ++fn)
            #pragma unroll
            for (int r2 = 0; r2 < 4; ++r2) {
                int ml = wr * WM + fm * 16 + l4 * 4 + r2;
                int nl = wc * WN + fn * 16 + l15;
                int m = m0 + ml, n = n0 + nl;
                float v = acc[fm][fn][r2];
                if constexpr (EPI == 0) {
                    outH[(size_t)m * ldo + n] = bfs(v + bias[n]);
                } else if constexpr (EPI == 1) {
                    outH[(size_t)m * ldo + n] = bfs(v);
                } else if constexpr (EPI == 3) {
                    if (n < Vv) {
                        bool mk = trow_ < lens[ml] - 1;
                        outF[((size_t)ml * Tt + trow_) * Vv + n] = mk ? (v + bias[n]) : 0.f;
                    }
                } else if constexpr (EPI == 6) {
                    if (n < 512) {
                        outH2[(size_t)m * KXN + 2048 + n] = bfs(v + bias[n]);
                    } else {
                        outF2[(size_t)m * 512 + (n - 512)] = v + bias2[n - 512];
                    }
                }
            }
}

// ---------------------------------------------------------------------------
// KA: per-(b,half) block, 512 threads.
//  1. h[b] (bf16) -> LDS f32
//  2. att2[b][tid]: dot over decKN[k][tid] (coalesced across lanes, h[k]
//     broadcast from LDS) -> sa2 (+dec_b)
//     gate[b][d0..d0+1]: betaKN[k][d0] uint32 loads -> regs (sigmoid +beta_b)
//  3. e = relu(att1+att2)@att_w + att_b; softmax -> sal (+alpha out, half 0)
//  4. awe: this half's 1024 cols, gate-multiplied, -> xin bf16
// ---------------------------------------------------------------------------
__global__ __launch_bounds__(512) void att_awe_k(
    const short* __restrict__ att1b, const short* __restrict__ decKN,
    const short* __restrict__ betaKN,
    const float* __restrict__ dec_b, const float* __restrict__ beta_b,
    const float* __restrict__ att_w, const float* __restrict__ att_b,
    const short* __restrict__ featb, short* __restrict__ xin,
    float* __restrict__ al_out, const int* __restrict__ lens, int t)
{
    const int b = blockIdx.y, half = blockIdx.x;
    const int tid = threadIdx.x, lane = tid & 63, wid = tid >> 6;
    __shared__ float sh[512];
    __shared__ float sa2[512];
    __shared__ float se[224];
    __shared__ float sred[256];
    __shared__ float sal[224];

    // h row -> LDS f32
    if (tid < 256) {
        uint32_t v = ((const uint32_t*)(xin + (size_t)b * KXN + 2048))[tid];
        float lo, hi;
        upk(v, lo, hi);
        sh[tid * 2] = lo;
        sh[tid * 2 + 1] = hi;
    }
    __syncthreads();

    // att2 (col tid) + gate (cols d0,d0+1) matvec, [k][n] coalesced weights
    const int d0 = half * 1024 + tid * 2;
    float accA = 0.f, acc0 = 0.f, acc1 = 0.f;
    {
        const short* pa = decKN + tid;
        const short* pg = betaKN + d0;
        #pragma unroll 8
        for (int k = 0; k < 512; ++k) {
            float hk = sh[k];
            accA += fbs(pa[(size_t)k * 512]) * hk;
            uint32_t g = *(const uint32_t*)(pg + (size_t)k * 2048);
            float lo, hi;
            upk(g, lo, hi);
            acc0 += lo * hk;
            acc1 += hi * hk;
        }
    }
    sa2[tid] = accA + dec_b[tid];
    float g0 = 1.f / (1.f + expf(-(acc0 + beta_b[d0])));
    float g1 = 1.f / (1.f + expf(-(acc1 + beta_b[d0 + 1])));
    __syncthreads();

    // e-dot: waves stride p by 8
    float aw[8], a2[8];
    #pragma unroll
    for (int j = 0; j < 8; ++j) {
        aw[j] = att_w[lane * 8 + j];
        a2[j] = sa2[lane * 8 + j];
    }
    float ab = att_b[0];
    for (int p = wid; p < Pp; p += 8) {
        s16x8 row = *(const s16x8*)&att1b[((size_t)b * Pp + p) * 512 + lane * 8];
        float s = 0.f;
        #pragma unroll
        for (int j = 0; j < 8; ++j) {
            float v = fbs(row[j]) + a2[j];
            v = v > 0.f ? v : 0.f;
            s += v * aw[j];
        }
        #pragma unroll
        for (int m = 32; m; m >>= 1) s += __shfl_xor(s, m);
        if (lane == 0) se[p] = s + ab;
    }
    __syncthreads();

    // softmax over 196
    float e = 0.f, ex = 0.f;
    if (tid < 256) {
        e = (tid < Pp) ? se[tid] : -3.0e38f;
        sred[tid] = e;
    }
    __syncthreads();
    for (int st = 128; st > 0; st >>= 1) {
        if (tid < st) sred[tid] = fmaxf(sred[tid], sred[tid + st]);
        __syncthreads();
    }
    float mx = sred[0];
    __syncthreads();
    if (tid < 256) {
        ex = (tid < Pp) ? expf(e - mx) : 0.f;
        sred[tid] = ex;
    }
    __syncthreads();
    for (int st = 128; st > 0; st >>= 1) {
        if (tid < st) sred[tid] += sred[tid + st];
        __syncthreads();
    }
    float inv = 1.f / sred[0];
    if (tid < Pp) {
        float al = ex * inv;
        sal[tid] = al;
        if (half == 0) {
            float mf = (t < lens[b] - 1) ? 1.f : 0.f;
            al_out[((size_t)b * Tt + t) * Pp + tid] = al * mf;
        }
    }
    __syncthreads();

    // awe over this half's 1024 cols
    const short* f = featb + (size_t)b * Pp * Dd + d0;
    float s0 = 0.f, s1 = 0.f;
    #pragma unroll 4
    for (int p = 0; p < Pp; ++p) {
        uint32_t v = *(const uint32_t*)(f + (size_t)p * Dd);
        float lo, hi;
        upk(v, lo, hi);
        float al = sal[p];
        s0 += al * lo;
        s1 += al * hi;
    }
    uint32_t o = ((uint32_t)(uint16_t)bfs(g1 * s1) << 16) | (uint16_t)bfs(g0 * s0);
    *(uint32_t*)(xin + (size_t)b * KXN + d0) = o;
}

// ---------------------------------------------------------------------------
// KB: gates = xin @ combT (quad-permuted) + eprec + biases -> LSTM update.
// grid 256: m0 = (bid&3)*32, n0 = (bid>>2)*32. K = 2560.
// Pipelined k-loop: 2x-unrolled register double-buffer.
// ---------------------------------------------------------------------------
__global__ __launch_bounds__(256) void gates_lstm_k(
    const short* __restrict__ xin, const short* __restrict__ combT,
    const short* __restrict__ eprec,
    const float* __restrict__ b_ih, const float* __restrict__ b_hh,
    float* __restrict__ c_state, short* __restrict__ hnew_all,
    short* __restrict__ xin_h, const int* __restrict__ lens, int t)
{
    constexpr int BM = 32, BN = 32, BK = 128, K = KXN;   // 2560 = 20 * 128
    constexpr int NCH = BK / 8;                          // 16
    constexpr int AU = NCH * BM;                         // 512 16B-units
    __shared__ __align__(16) short sA[AU * 8];
    __shared__ __align__(16) short sB[AU * 8];

    const int m0 = ((int)blockIdx.x & 3) * BM, n0 = ((int)blockIdx.x >> 2) * BN;
    const int tid = threadIdx.x, lane = tid & 63, wid = tid >> 6;
    const int l15 = lane & 15, l4 = lane >> 4;
    const int wr = wid >> 1, wc = wid & 1;               // WR=2, WC=2

    f32x4 acc = {0.f, 0.f, 0.f, 0.f};
    const int r2 = tid / NCH, ch0 = tid % NCH;           // rows r2, r2+16
    const short* Abase = xin + (size_t)(m0 + r2) * KXN + ch0 * 8;
    const short* Bbase = combT + (size_t)(n0 + r2) * KXN + ch0 * 8;
    const size_t rowadv = (size_t)16 * KXN;

    s16x8 raA0, raA1, rbA0, rbA1, raB0, raB1, rbB0, rbB1;

    auto loadA = [&](int kt, s16x8& a0, s16x8& a1, s16x8& b0, s16x8& b1) {
        a0 = *(const s16x8*)(Abase + kt);
        a1 = *(const s16x8*)(Abase + rowadv + kt);
        b0 = *(const s16x8*)(Bbase + kt);
        b1 = *(const s16x8*)(Bbase + rowadv + kt);
    };
    const int sl0 = ((r2) * NCH + (ch0 ^ (r2 & 7))) * 8;
    const int sl1 = ((r2 + 16) * NCH + (ch0 ^ ((r2 + 16) & 7))) * 8;
    auto storeS = [&](s16x8& a0, s16x8& a1, s16x8& b0, s16x8& b1) {
        *(s16x8*)(sA + sl0) = a0;
        *(s16x8*)(sA + sl1) = a1;
        *(s16x8*)(sB + sl0) = b0;
        *(s16x8*)(sB + sl1) = b1;
    };
    const int rrA = wr * 16 + l15, rrB = wc * 16 + l15;
    auto mfmaS = [&]() {
        #pragma unroll
        for (int ks = 0; ks < BK / 32; ++ks) {
            int cc = ks * 4 + l4;
            s16x8 af = *(const s16x8*)&sA[(rrA * NCH + (cc ^ (rrA & 7))) * 8];
            s16x8 bf = *(const s16x8*)&sB[(rrB * NCH + (cc ^ (rrB & 7))) * 8];
            acc = __builtin_amdgcn_mfma_f32_16x16x32_bf16(af, bf, acc, 0, 0, 0);
        }
    };

    loadA(0, raA0, raA1, rbA0, rbA1);
    #pragma unroll 1
    for (int kt = 0; kt < K; kt += 2 * BK) {
        __syncthreads();
        storeS(raA0, raA1, rbA0, rbA1);
        __syncthreads();
        if (kt + BK < K) loadA(kt + BK, raB0, raB1, rbB0, rbB1);
        mfmaS();
        __syncthreads();
        storeS(raB0, raB1, rbB0, rbB1);
        __syncthreads();
        if (kt + 2 * BK < K) loadA(kt + 2 * BK, raA0, raA1, rbA0, rbA1);
        mfmaS();
    }

    // LSTM epilogue via LDS round-trip (quad-permuted cols: q = n0/4 + jl)
    __syncthreads();
    float* sE = (float*)sA;
    #pragma unroll
    for (int r = 0; r < 4; ++r) {
        int ml = wr * 16 + l4 * 4 + r, nl = wc * 16 + l15;
        sE[ml * 32 + nl] = acc[r];
    }
    __syncthreads();
    int bl = tid >> 3, jl = tid & 7;
    int b = m0 + bl, q = (n0 >> 2) + jl;
    f32x4 ge = *(const f32x4*)&sE[bl * 32 + jl * 4];
    short4 ep = *(const short4*)&eprec[((size_t)t * 128 + b) * 2048 + n0 + jl * 4];
    float gi = ge[0] + fbs(ep.x) + b_ih[q]        + b_hh[q];
    float gf = ge[1] + fbs(ep.y) + b_ih[512 + q]  + b_hh[512 + q];
    float gg = ge[2] + fbs(ep.z) + b_ih[1024 + q] + b_hh[1024 + q];
    float go = ge[3] + fbs(ep.w) + b_ih[1536 + q] + b_hh[1536 + q];
    float si = 1.f / (1.f + expf(-gi));
    float sf = 1.f / (1.f + expf(-gf));
    float so = 1.f / (1.f + expf(-go));
    float tg = tanhf(gg);
    int sidx = b * 512 + q;
    float cn = sf * c_state[sidx] + si * tg;
    float hn = so * tanhf(cn);
    hnew_all[((size_t)t * 128 + b) * 512 + q] = bfs(hn);
    if (t < lens[b] - 1) {
        c_state[sidx] = cn;
        xin_h[(size_t)b * KXN + 2048 + q] = bfs(hn);
    }
}

// ---------------------------------------------------------------------------
// conv/mean: features fp32 -> bf16, bf16 mean over P.  grid (4,128), 2 d/thr.
// ---------------------------------------------------------------------------
__global__ __launch_bounds__(256) void conv_mean_k(
    const float* __restrict__ feat, short* __restrict__ featb, short* __restrict__ meanb)
{
    int b = blockIdx.y;
    int d = (blockIdx.x * 256 + threadIdx.x) * 2;
    const float* f = feat + (size_t)b * Pp * Dd + d;
    short* o = featb + (size_t)b * Pp * Dd + d;
    float s0 = 0.f, s1 = 0.f;
    #pragma unroll 4
    for (int p = 0; p < Pp; ++p) {
        float2 v = *(const float2*)(f + (size_t)p * Dd);
        s0 += v.x; s1 += v.y;
        uint32_t ov = ((uint32_t)(uint16_t)bfs(v.y) << 16) | (uint16_t)bfs(v.x);
        *(uint32_t*)(o + (size_t)p * Dd) = ov;
    }
    const float inv = 1.f / 196.f;
    uint32_t mv = ((uint32_t)(uint16_t)bfs(s1 * inv) << 16) | (uint16_t)bfs(s0 * inv);
    *(uint32_t*)(meanb + (size_t)b * Dd + d) = mv;
}

// ---------------------------------------------------------------------------
// prep_k: weight transposes + straight casts + embedding gather, ONE launch.
// Section boundaries are ABSOLUTE block ids; grid must be 20384.
// ---------------------------------------------------------------------------
DEV void t32(const float* __restrict__ src, int R, int C,
             short* __restrict__ dst, int ds, int off, int perm,
             int local, int gx, float (*tile)[33])
{
    int x = local % gx, y = local / gx;
    int c0 = x * 32, r0 = y * 32;
    int tx = threadIdx.x & 31, ty = threadIdx.x >> 5;
    #pragma unroll
    for (int i = 0; i < 4; ++i) {
        int r = r0 + ty + i * 8, c = c0 + tx;
        tile[ty + i * 8][tx] = (r < R && c < C) ? src[(size_t)r * C + c] : 0.f;
    }
    __syncthreads();
    #pragma unroll
    for (int i = 0; i < 4; ++i) {
        int cc = c0 + ty + i * 8, rr = r0 + tx;
        if (rr < R) {
            int drow = perm ? ((cc & 511) * 4 + (cc >> 9)) : cc;
            dst[(size_t)drow * ds + off + rr] = bfs(tile[tx][ty + i * 8]);
        }
    }
}

DEV void castf4(const float* __restrict__ src, short* __restrict__ dst, int local) {
    int i = local * 256 + threadIdx.x;
    float4 v = *(const float4*)(src + (size_t)i * 4);
    short4 o = make_short4(bfs(v.x), bfs(v.y), bfs(v.z), bfs(v.w));
    *(short4*)(dst + (size_t)i * 4) = o;
}

__global__ __launch_bounds__(256) void prep_k(
    const float* __restrict__ enc_w, const float* __restrict__ h_fc_w,
    const float* __restrict__ c_fc_w, const float* __restrict__ dec_w,
    const float* __restrict__ beta_w, const float* __restrict__ w_ih,
    const float* __restrict__ w_hh, const float* __restrict__ cls_w,
    const float* __restrict__ emb, const int* __restrict__ caps,
    short* __restrict__ encT, short* __restrict__ hcT,
    short* __restrict__ decKN, short* __restrict__ betaKN,
    short* __restrict__ combT, short* __restrict__ wtopT, short* __restrict__ clsT,
    short* __restrict__ embseq)
{
    __shared__ float tile[32][33];
    int bid = blockIdx.x;
    if (bid < 1024)        t32(enc_w, 2048, 512, encT, 2048, 0, 0, bid, 16, tile);
    else if (bid < 2048)   t32(h_fc_w, 2048, 512, hcT, 2048, 0, 0, bid - 1024, 16, tile);
    else if (bid < 3072)   t32(c_fc_w, 2048, 512, hcT + (size_t)512 * 2048, 2048, 0, 0, bid - 2048, 16, tile);
    else if (bid < 3328)   castf4(dec_w, decKN, bid - 3072);       // 512*512
    else if (bid < 4352)   castf4(beta_w, betaKN, bid - 3328);     // 512*2048
    else if (bid < 8448)   t32(w_ih + (size_t)512 * 2048, 2048, 2048, combT, KXN, 0, 1, bid - 4352, 64, tile);
    else if (bid < 9472)   t32(w_hh, 512, 2048, combT, KXN, 2048, 1, bid - 8448, 64, tile);
    else if (bid < 10496)  t32(w_ih, 512, 2048, wtopT, 512, 0, 1, bid - 9472, 64, tile);
    else if (bid < 15520)  t32(cls_w, 512, 10000, clsT, 512, 0, 0, bid - 10496, 314, tile);
    else {
        size_t i = (size_t)(bid - 15520) * 256 + threadIdx.x;
        if (i < (size_t)Tt * Bb * Ee) {
            int e = (int)(i % Ee);
            size_t r = i / Ee;
            int b = (int)(r % Bb);
            int t = (int)(r / Bb);
            int cap = caps[b * TMAX + t];
            embseq[i] = bfs(emb[(size_t)cap * Ee + e]);
        }
    }
}

// ---------------------------------------------------------------------------
extern "C" void kernel_launch(void* const* d_in, const int* in_sizes, int n_in,
                              void* d_out, int out_size, void* d_ws, size_t ws_size,
                              hipStream_t stream)
{
    const float* features = (const float*)d_in[0];
    const int* captions   = (const int*)d_in[1];
    const int* lengths    = (const int*)d_in[2];
    const float* emb      = (const float*)d_in[3];
    const float* h_fc_w   = (const float*)d_in[4];
    const float* h_fc_b   = (const float*)d_in[5];
    const float* c_fc_w   = (const float*)d_in[6];
    const float* c_fc_b   = (const float*)d_in[7];
    const float* enc_w    = (const float*)d_in[8];
    const float* enc_b    = (const float*)d_in[9];
    const float* dec_w    = (const float*)d_in[10];
    const float* dec_b    = (const float*)d_in[11];
    const float* att_w    = (const float*)d_in[12];
    const float* att_b    = (const float*)d_in[13];
    const float* beta_w   = (const float*)d_in[14];
    const float* beta_b   = (const float*)d_in[15];
    const float* w_ih     = (const float*)d_in[16];
    const float* b_ih     = (const float*)d_in[17];
    const float* w_hh     = (const float*)d_in[18];
    const float* b_hh     = (const float*)d_in[19];
    const float* cls_w    = (const float*)d_in[20];
    const float* cls_b    = (const float*)d_in[21];

    char* w = (char*)d_ws;
    auto alloc = [&](size_t bytes) {
        char* p = w;
        w += (bytes + 255) & ~(size_t)255;
        return p;
    };
    short* featb    = (short*)alloc((size_t)Bb * Pp * Dd * 2);
    short* att1b    = (short*)alloc((size_t)Bb * Pp * Aa * 2);
    short* encT     = (short*)alloc((size_t)Aa * Dd * 2);
    short* combT    = (short*)alloc((size_t)2048 * KXN * 2);   // quad-perm rows
    short* wtopT    = (short*)alloc((size_t)2048 * 512 * 2);   // quad-perm rows
    short* clsT     = (short*)alloc((size_t)NVP * Hh * 2);
    short* decKN    = (short*)alloc((size_t)512 * 512 * 2);    // [k][n] cast
    short* betaKN   = (short*)alloc((size_t)512 * 2048 * 2);   // [k][n] cast
    short* hcT      = (short*)alloc((size_t)1024 * Dd * 2);    // [h_fc;c_fc]
    short* embseq   = (short*)alloc((size_t)Tt * Bb * Ee * 2);
    short* meanb    = (short*)alloc((size_t)Bb * Dd * 2);
    short* eprec    = (short*)alloc((size_t)Tt * Bb * 2048 * 2);
    float* c_state  = (float*)alloc((size_t)Bb * Hh * 4);
    short* xin      = (short*)alloc((size_t)Bb * KXN * 2);
    short* hnew_all = (short*)alloc((size_t)Tt * Bb * Hh * 2);

    float* y_out  = (float*)d_out;
    float* al_out = y_out + (size_t)Bb * Tt * Vv;

    // ---- precompute (5 launches) ----
    conv_mean_k<<<dim3(4, 128), 256, 0, stream>>>(features, featb, meanb);
    prep_k<<<dim3(20384), 256, 0, stream>>>(
        enc_w, h_fc_w, c_fc_w, dec_w, beta_w, w_ih, w_hh, cls_w, emb, captions,
        encT, hcT, decKN, betaKN, combT, wtopT, clsT, embseq);

    // h0/c0 GEMM: meanb @ hcT^T (EPI 6) -> xin h-slot + c_state
    gemm_k<128, 64, 64, 256, 2, 2, 6><<<dim3(16, 1), 256, 0, stream>>>(
        meanb, 2048, hcT, 2048, 2048,
        nullptr, c_state, nullptr, xin, 0, h_fc_b, c_fc_b, nullptr);

    // att1 = features @ enc_w + enc_b (bf16), XCD-chunked 392-block grid
    gemm_k<128, 256, 64, 512, 2, 4, 0><<<dim3(392), 512, 0, stream>>>(
        featb, 2048, encT, 2048, 2048,
        nullptr, nullptr, att1b, nullptr, Aa, enc_b, nullptr, nullptr);

    // eprec = embseq @ wtopT^T (bf16, quad-permuted cols), all 19 steps
    gemm_k<128, 64, 64, 256, 2, 2, 1><<<dim3(32, 19), 256, 0, stream>>>(
        embseq, 512, wtopT, 512, 512,
        nullptr, nullptr, eprec, nullptr, 2048, nullptr, nullptr, nullptr);

    // ---- decode steps: 2 launches each ----
    for (int t = 0; t < Tt; ++t) {
        att_awe_k<<<dim3(2, 128), 512, 0, stream>>>(
            att1b, decKN, betaKN, dec_b, beta_b, att_w, att_b, featb, xin,
            al_out, lengths, t);
        gates_lstm_k<<<dim3(256), 256, 0, stream>>>(
            xin, combT, eprec, b_ih, b_hh, c_state, hnew_all, xin, lengths, t);
    }

    // deferred y: hnew_all[2432][512] @ clsT^T, XCD-chunked
    gemm_k<128, 64, 64, 256, 2, 2, 3><<<dim3(157 * Tt), 256, 0, stream>>>(
        hnew_all, 512, clsT, 512, 512,
        y_out, nullptr, nullptr, nullptr, 0, cls_b, nullptr, lengths);
}

// Round 10
// 1355.617 us; speedup vs baseline: 1.2815x; 1.2815x over previous
//
#include <hip/hip_runtime.h>
#include <cstdint>
#include <cstddef>

// ---------------------------------------------------------------------------
// Show-Attend-Tell decoder on MI355X (round 10).
// 3 launches per decode step (round-4 structure, proven 1475us):
//   K1 gemm EPI4: h @ [dec | beta | W_hh(qp)]  (N=4608, K=512, 288 blocks)
//       -> att2b f32, gatebuf sigmoid f32, hpart f32 (quad-perm cols)
//   K2 att_awe_k: e/relu/softmax + awe (grid (2,128), 512 thr)
//   KB gates_lstm_k: awe @ W_ih_bot (K=2048) + hpart + eprec + LSTM
// Precompute: conv_mean, prep_k, h0c0 GEMM, att1 GEMM, eprec GEMM; y deferred.
// NOTES (post-mortems):
//  - r3: persistent coop kernel w/ agent-scope spin barrier = ~125us/barrier
//    + cache-invalidate storms (threadfence wbinv). Do NOT revisit.
//  - r4: inter-launch gap ~8us -> minimize launches on sequential chain.
//  - r6: matvec with [n][k] weights = uncoalesced, +45us/step.
//  - r9: per-b matvec fusion multiplies weight traffic by B/BM (384MB/step),
//    +14us/step vs GEMM. Weight-streaming ops MUST be m-tiled GEMMs.
// ---------------------------------------------------------------------------

#define DEV __device__ __forceinline__

typedef __attribute__((ext_vector_type(8))) short s16x8;
typedef __attribute__((ext_vector_type(4))) float f32x4;

constexpr int Bb = 128, Pp = 196, Dd = 2048, Aa = 512, Ee = 512, Hh = 512, Vv = 10000;
constexpr int Tt = 19, TMAX = 20;
constexpr int NVP = 10048;

DEV float fbs(short s) {
    union { uint32_t u; float f; } v;
    v.u = ((uint32_t)(uint16_t)s) << 16;
    return v.f;
}
DEV short bfs(float f) {
    union { float f; uint32_t u; } v;
    v.f = f;
    uint32_t u = v.u;
    uint32_t r = (u + 0x7FFFu + ((u >> 16) & 1u)) >> 16;  // RNE
    return (short)(uint16_t)r;
}
DEV void upk(uint32_t v, float& lo, float& hi) {
    union { uint32_t u; float f; } a, b;
    a.u = v << 16;
    b.u = v & 0xffff0000u;
    lo = a.f;
    hi = b.f;
}

// ---------------------------------------------------------------------------
// GEMM template. B stored [N][K]. LDS XOR-swizzled.
// EPI: 0 = bf16 out + bias, XCD-chunked 1-D grid (att1; 392 blocks)
//      1 = bf16 out, no bias (eprec)
//      3 = deferred y with mask (1-D XCD-chunked grid 157*19)
//      4 = K1: 1-D grid 288; n<512 -> att2b f32 (+dec_b);
//          512<=n<2560 -> gatebuf sigmoid (+beta_b); else hpart f32 (no bias)
//      6 = h0c0: n<512 -> hb16 (+h_fc_b); else c_state (+c_fc_b)
// ---------------------------------------------------------------------------
template<int BM, int BN, int BK, int TH, int WR, int WC, int EPI>
__global__ __launch_bounds__(TH) void gemm_k(
    const short* __restrict__ Ag, int lda,
    const short* __restrict__ Bg, int ldb,
    int K,
    float* __restrict__ outF, float* __restrict__ outF2,
    short* __restrict__ outH, short* __restrict__ outH2,
    int ldo,
    const float* __restrict__ bias, const float* __restrict__ bias2,
    const int* __restrict__ lens)
{
    constexpr int NCH = BK / 8;
    constexpr int AU = NCH * BM, BU = NCH * BN;
    constexpr int APT = AU / TH, BPT = BU / TH;
    constexpr int WM = BM / WR, WN = BN / WC;
    constexpr int FM = WM / 16, FN = WN / 16;

    __shared__ __align__(16) short sA[AU * 8];
    __shared__ __align__(16) short sB[BU * 8];

    const int tid = threadIdx.x, lane = tid & 63, wid = tid >> 6;
    const int l15 = lane & 15, l4 = lane >> 4;

    int m0, n0, trow_ = 0;
    if constexpr (EPI == 0) {
        int task = (blockIdx.x & 7) * 49 + (blockIdx.x >> 3);   // 392 blocks
        m0 = (task >> 1) * BM;
        n0 = (task & 1) * BN;
    } else if constexpr (EPI == 3) {
        const int nwg = (int)gridDim.x;                         // 157*19
        const int qq = nwg >> 3, rr = nwg & 7;
        int xcd = (int)blockIdx.x & 7, idx = (int)blockIdx.x >> 3;
        int task = (xcd < rr) ? xcd * (qq + 1) + idx
                              : rr * (qq + 1) + (xcd - rr) * qq + idx;
        int npanel = task / Tt;
        trow_ = task - npanel * Tt;
        m0 = trow_ * BM;
        n0 = npanel * BN;
    } else if constexpr (EPI == 4) {
        m0 = ((int)blockIdx.x & 3) * BM;
        n0 = ((int)blockIdx.x >> 2) * BN;
    } else {
        m0 = blockIdx.y * BM;
        n0 = blockIdx.x * BN;
    }
    const int wr = wid / WC, wc = wid % WC;

    f32x4 acc[FM][FN];
    #pragma unroll
    for (int i = 0; i < FM; ++i)
        #pragma unroll
        for (int j = 0; j < FN; ++j) acc[i][j] = {0.f, 0.f, 0.f, 0.f};

    for (int kt = 0; kt < K; kt += BK) {
        s16x8 ra[APT], rb[BPT];
        #pragma unroll
        for (int i = 0; i < APT; ++i) {
            int q2 = tid + TH * i;
            int r2 = q2 / NCH, ch = q2 % NCH;
            ra[i] = *(const s16x8*)(Ag + (size_t)(m0 + r2) * lda + kt + ch * 8);
        }
        #pragma unroll
        for (int i = 0; i < BPT; ++i) {
            int q2 = tid + TH * i;
            int r2 = q2 / NCH, ch = q2 % NCH;
            rb[i] = *(const s16x8*)(Bg + (size_t)(n0 + r2) * ldb + kt + ch * 8);
        }
        __syncthreads();
        #pragma unroll
        for (int i = 0; i < APT; ++i) {
            int q2 = tid + TH * i;
            int r2 = q2 / NCH, ch = q2 % NCH;
            *(s16x8*)(sA + (r2 * NCH + (ch ^ (r2 & 7))) * 8) = ra[i];
        }
        #pragma unroll
        for (int i = 0; i < BPT; ++i) {
            int q2 = tid + TH * i;
            int r2 = q2 / NCH, ch = q2 % NCH;
            *(s16x8*)(sB + (r2 * NCH + (ch ^ (r2 & 7))) * 8) = rb[i];
        }
        __syncthreads();
        #pragma unroll
        for (int ks = 0; ks < BK / 32; ++ks) {
            s16x8 af[FM], bf[FN];
            #pragma unroll
            for (int fm = 0; fm < FM; ++fm) {
                int rr2 = wr * WM + fm * 16 + l15, cc = ks * 4 + l4;
                af[fm] = *(const s16x8*)&sA[(rr2 * NCH + (cc ^ (rr2 & 7))) * 8];
            }
            #pragma unroll
            for (int fn = 0; fn < FN; ++fn) {
                int rr2 = wc * WN + fn * 16 + l15, cc = ks * 4 + l4;
                bf[fn] = *(const s16x8*)&sB[(rr2 * NCH + (cc ^ (rr2 & 7))) * 8];
            }
            #pragma unroll
            for (int fm = 0; fm < FM; ++fm)
                #pragma unroll
                for (int fn = 0; fn < FN; ++fn)
                    acc[fm][fn] = __builtin_amdgcn_mfma_f32_16x16x32_bf16(af[fm], bf[fn], acc[fm][fn], 0, 0, 0);
        }
        __syncthreads();
    }

    #pragma unroll
    for (int fm = 0; fm < FM; ++fm)
        #pragma unroll
        for (int fn = 0; fn < FN; ++fn)
            #pragma unroll
            for (int r2 = 0; r2 < 4; ++r2) {
                int ml = wr * WM + fm * 16 + l4 * 4 + r2;
                int nl = wc * WN + fn * 16 + l15;
                int m = m0 + ml, n = n0 + nl;
                float v = acc[fm][fn][r2];
                if constexpr (EPI == 0) {
                    outH[(size_t)m * ldo + n] = bfs(v + bias[n]);
                } else if constexpr (EPI == 1) {
                    outH[(size_t)m * ldo + n] = bfs(v);
                } else if constexpr (EPI == 3) {
                    if (n < Vv) {
                        bool mk = trow_ < lens[ml] - 1;
                        outF[((size_t)ml * Tt + trow_) * Vv + n] = mk ? (v + bias[n]) : 0.f;
                    }
                } else if constexpr (EPI == 4) {
                    if (n < 512) outF[(size_t)m * Aa + n] = v + bias[n];
                    else if (n < 2560)
                        outF2[(size_t)m * Dd + (n - 512)] =
                            1.f / (1.f + expf(-(v + bias2[n - 512])));
                    else
                        ((float*)outH)[(size_t)m * 2048 + (n - 2560)] = v;  // hpart
                } else if constexpr (EPI == 6) {
                    if (n < 512) {
                        outH2[(size_t)m * 512 + n] = bfs(v + bias[n]);      // hb16
                    } else {
                        outF2[(size_t)m * 512 + (n - 512)] = v + bias2[n - 512]; // c_state
                    }
                }
            }
}

// ---------------------------------------------------------------------------
// K2: fused e = relu(att1+att2)@att_w + att_b -> softmax -> alpha -> awe.
// grid (2, 128), 512 threads. Each block: full e/softmax (redundant per half),
// half the awe d-range (1024 cols). alpha output written by half 0 only.
// ---------------------------------------------------------------------------
__global__ __launch_bounds__(512) void att_awe_k(
    const short* __restrict__ att1b, const float* __restrict__ att2b,
    const float* __restrict__ att_w, const float* __restrict__ att_b,
    const short* __restrict__ featb, const float* __restrict__ gatebuf,
    short* __restrict__ xin, float* __restrict__ al_out,
    const int* __restrict__ lens, int t)
{
    const int b = blockIdx.y, half = blockIdx.x;
    const int tid = threadIdx.x, lane = tid & 63, wid = tid >> 6;
    __shared__ float se[224];
    __shared__ float sred[256];
    __shared__ float sal[224];

    float aw[8], a2[8];
    #pragma unroll
    for (int j = 0; j < 8; ++j) {
        aw[j] = att_w[lane * 8 + j];
        a2[j] = att2b[b * 512 + lane * 8 + j];
    }
    float ab = att_b[0];
    for (int p = wid; p < Pp; p += 8) {
        s16x8 row = *(const s16x8*)&att1b[((size_t)b * Pp + p) * 512 + lane * 8];
        float s = 0.f;
        #pragma unroll
        for (int j = 0; j < 8; ++j) {
            float v = fbs(row[j]) + a2[j];
            v = v > 0.f ? v : 0.f;
            s += v * aw[j];
        }
        #pragma unroll
        for (int m = 32; m; m >>= 1) s += __shfl_xor(s, m);
        if (lane == 0) se[p] = s + ab;
    }
    __syncthreads();
    float e = 0.f, ex = 0.f;
    if (tid < 256) {
        e = (tid < Pp) ? se[tid] : -3.0e38f;
        sred[tid] = e;
    }
    __syncthreads();
    for (int st = 128; st > 0; st >>= 1) {
        if (tid < st) sred[tid] = fmaxf(sred[tid], sred[tid + st]);
        __syncthreads();
    }
    float mx = sred[0];
    __syncthreads();
    if (tid < 256) {
        ex = (tid < Pp) ? expf(e - mx) : 0.f;
        sred[tid] = ex;
    }
    __syncthreads();
    for (int st = 128; st > 0; st >>= 1) {
        if (tid < st) sred[tid] += sred[tid + st];
        __syncthreads();
    }
    float inv = 1.f / sred[0];
    if (tid < Pp) {
        float al = ex * inv;
        sal[tid] = al;
        if (half == 0) {
            float mf = (t < lens[b] - 1) ? 1.f : 0.f;
            al_out[((size_t)b * Tt + t) * Pp + tid] = al * mf;
        }
    }
    __syncthreads();
    // awe over this half's 1024 cols
    int d0 = half * 1024 + tid * 2;
    const short* f = featb + (size_t)b * Pp * Dd + d0;
    float s0 = 0.f, s1 = 0.f;
    #pragma unroll 4
    for (int p = 0; p < Pp; ++p) {
        uint32_t v = *(const uint32_t*)(f + (size_t)p * Dd);
        float lo, hi;
        upk(v, lo, hi);
        float al = sal[p];
        s0 += al * lo;
        s1 += al * hi;
    }
    float2 g = *(const float2*)&gatebuf[b * 2048 + d0];
    uint32_t o = ((uint32_t)(uint16_t)bfs(g.y * s1) << 16) | (uint16_t)bfs(g.x * s0);
    *(uint32_t*)(xin + (size_t)b * 2048 + d0) = o;
}

// ---------------------------------------------------------------------------
// KB: gates = xin(awe) @ combT (quad-perm, K=2048) + hpart + eprec + biases
//     -> LSTM update. grid 256: m0=(bid&3)*32, n0=(bid>>2)*32.
// Pipelined k-loop: 2x-unrolled register double-buffer.
// ---------------------------------------------------------------------------
__global__ __launch_bounds__(256) void gates_lstm_k(
    const short* __restrict__ xin, const short* __restrict__ combT,
    const short* __restrict__ eprec, const float* __restrict__ hpart,
    const float* __restrict__ b_ih, const float* __restrict__ b_hh,
    float* __restrict__ c_state, short* __restrict__ hnew_all,
    short* __restrict__ hb16, const int* __restrict__ lens, int t)
{
    constexpr int BM = 32, BN = 32, BK = 128, K = 2048;  // 2048 = 16 * 128
    constexpr int NCH = BK / 8;                          // 16
    constexpr int AU = NCH * BM;                         // 512 16B-units
    __shared__ __align__(16) short sA[AU * 8];
    __shared__ __align__(16) short sB[AU * 8];

    const int m0 = ((int)blockIdx.x & 3) * BM, n0 = ((int)blockIdx.x >> 2) * BN;
    const int tid = threadIdx.x, lane = tid & 63, wid = tid >> 6;
    const int l15 = lane & 15, l4 = lane >> 4;
    const int wr = wid >> 1, wc = wid & 1;               // WR=2, WC=2

    f32x4 acc = {0.f, 0.f, 0.f, 0.f};
    const int r2 = tid / NCH, ch0 = tid % NCH;           // rows r2, r2+16
    const short* Abase = xin + (size_t)(m0 + r2) * 2048 + ch0 * 8;
    const short* Bbase = combT + (size_t)(n0 + r2) * 2048 + ch0 * 8;
    const size_t rowadv = (size_t)16 * 2048;

    s16x8 raA0, raA1, rbA0, rbA1, raB0, raB1, rbB0, rbB1;

    auto loadA = [&](int kt, s16x8& a0, s16x8& a1, s16x8& b0, s16x8& b1) {
        a0 = *(const s16x8*)(Abase + kt);
        a1 = *(const s16x8*)(Abase + rowadv + kt);
        b0 = *(const s16x8*)(Bbase + kt);
        b1 = *(const s16x8*)(Bbase + rowadv + kt);
    };
    const int sl0 = ((r2) * NCH + (ch0 ^ (r2 & 7))) * 8;
    const int sl1 = ((r2 + 16) * NCH + (ch0 ^ ((r2 + 16) & 7))) * 8;
    auto storeS = [&](s16x8& a0, s16x8& a1, s16x8& b0, s16x8& b1) {
        *(s16x8*)(sA + sl0) = a0;
        *(s16x8*)(sA + sl1) = a1;
        *(s16x8*)(sB + sl0) = b0;
        *(s16x8*)(sB + sl1) = b1;
    };
    const int rrA = wr * 16 + l15, rrB = wc * 16 + l15;
    auto mfmaS = [&]() {
        #pragma unroll
        for (int ks = 0; ks < BK / 32; ++ks) {
            int cc = ks * 4 + l4;
            s16x8 af = *(const s16x8*)&sA[(rrA * NCH + (cc ^ (rrA & 7))) * 8];
            s16x8 bf = *(const s16x8*)&sB[(rrB * NCH + (cc ^ (rrB & 7))) * 8];
            acc = __builtin_amdgcn_mfma_f32_16x16x32_bf16(af, bf, acc, 0, 0, 0);
        }
    };

    loadA(0, raA0, raA1, rbA0, rbA1);
    #pragma unroll 1
    for (int kt = 0; kt < K; kt += 2 * BK) {
        __syncthreads();
        storeS(raA0, raA1, rbA0, rbA1);
        __syncthreads();
        if (kt + BK < K) loadA(kt + BK, raB0, raB1, rbB0, rbB1);
        mfmaS();
        __syncthreads();
        storeS(raB0, raB1, rbB0, rbB1);
        __syncthreads();
        if (kt + 2 * BK < K) loadA(kt + 2 * BK, raA0, raA1, rbA0, rbA1);
        mfmaS();
    }

    // LSTM epilogue via LDS round-trip (quad-permuted cols: q = n0/4 + jl)
    __syncthreads();
    float* sE = (float*)sA;
    #pragma unroll
    for (int r = 0; r < 4; ++r) {
        int ml = wr * 16 + l4 * 4 + r, nl = wc * 16 + l15;
        sE[ml * 32 + nl] = acc[r];
    }
    __syncthreads();
    int bl = tid >> 3, jl = tid & 7;
    int b = m0 + bl, q = (n0 >> 2) + jl;
    f32x4 ge = *(const f32x4*)&sE[bl * 32 + jl * 4];
    f32x4 hp = *(const f32x4*)&hpart[(size_t)b * 2048 + n0 + jl * 4];
    short4 ep = *(const short4*)&eprec[((size_t)t * 128 + b) * 2048 + n0 + jl * 4];
    float gi = ge[0] + hp[0] + fbs(ep.x) + b_ih[q]        + b_hh[q];
    float gf = ge[1] + hp[1] + fbs(ep.y) + b_ih[512 + q]  + b_hh[512 + q];
    float gg = ge[2] + hp[2] + fbs(ep.z) + b_ih[1024 + q] + b_hh[1024 + q];
    float go = ge[3] + hp[3] + fbs(ep.w) + b_ih[1536 + q] + b_hh[1536 + q];
    float si = 1.f / (1.f + expf(-gi));
    float sf = 1.f / (1.f + expf(-gf));
    float so = 1.f / (1.f + expf(-go));
    float tg = tanhf(gg);
    int sidx = b * 512 + q;
    float cn = sf * c_state[sidx] + si * tg;
    float hn = so * tanhf(cn);
    hnew_all[((size_t)t * 128 + b) * 512 + q] = bfs(hn);
    if (t < lens[b] - 1) {
        c_state[sidx] = cn;
        hb16[sidx] = bfs(hn);
    }
}

// ---------------------------------------------------------------------------
// conv/mean: features fp32 -> bf16, bf16 mean over P.  grid (4,128), 2 d/thr.
// ---------------------------------------------------------------------------
__global__ __launch_bounds__(256) void conv_mean_k(
    const float* __restrict__ feat, short* __restrict__ featb, short* __restrict__ meanb)
{
    int b = blockIdx.y;
    int d = (blockIdx.x * 256 + threadIdx.x) * 2;
    const float* f = feat + (size_t)b * Pp * Dd + d;
    short* o = featb + (size_t)b * Pp * Dd + d;
    float s0 = 0.f, s1 = 0.f;
    #pragma unroll 4
    for (int p = 0; p < Pp; ++p) {
        float2 v = *(const float2*)(f + (size_t)p * Dd);
        s0 += v.x; s1 += v.y;
        uint32_t ov = ((uint32_t)(uint16_t)bfs(v.y) << 16) | (uint16_t)bfs(v.x);
        *(uint32_t*)(o + (size_t)p * Dd) = ov;
    }
    const float inv = 1.f / 196.f;
    uint32_t mv = ((uint32_t)(uint16_t)bfs(s1 * inv) << 16) | (uint16_t)bfs(s0 * inv);
    *(uint32_t*)(meanb + (size_t)b * Dd + d) = mv;
}

// ---------------------------------------------------------------------------
// prep_k: weight transposes + embedding gather in ONE launch.
// Section boundaries are ABSOLUTE block ids; grid MUST be 20384 (r7 lesson).
// ---------------------------------------------------------------------------
DEV void t32(const float* __restrict__ src, int R, int C,
             short* __restrict__ dst, int ds, int off, int perm,
             int local, int gx, float (*tile)[33])
{
    int x = local % gx, y = local / gx;
    int c0 = x * 32, r0 = y * 32;
    int tx = threadIdx.x & 31, ty = threadIdx.x >> 5;
    #pragma unroll
    for (int i = 0; i < 4; ++i) {
        int r = r0 + ty + i * 8, c = c0 + tx;
        tile[ty + i * 8][tx] = (r < R && c < C) ? src[(size_t)r * C + c] : 0.f;
    }
    __syncthreads();
    #pragma unroll
    for (int i = 0; i < 4; ++i) {
        int cc = c0 + ty + i * 8, rr = r0 + tx;
        if (rr < R) {
            int drow = perm ? ((cc & 511) * 4 + (cc >> 9)) : cc;
            dst[(size_t)drow * ds + off + rr] = bfs(tile[tx][ty + i * 8]);
        }
    }
}

__global__ __launch_bounds__(256) void prep_k(
    const float* __restrict__ enc_w, const float* __restrict__ h_fc_w,
    const float* __restrict__ c_fc_w, const float* __restrict__ dec_w,
    const float* __restrict__ beta_w, const float* __restrict__ w_ih,
    const float* __restrict__ w_hh, const float* __restrict__ cls_w,
    const float* __restrict__ emb, const int* __restrict__ caps,
    short* __restrict__ encT, short* __restrict__ hcT, short* __restrict__ catT,
    short* __restrict__ combT, short* __restrict__ wtopT, short* __restrict__ clsT,
    short* __restrict__ embseq)
{
    __shared__ float tile[32][33];
    int bid = blockIdx.x;
    if (bid < 1024)        t32(enc_w, 2048, 512, encT, 2048, 0, 0, bid, 16, tile);
    else if (bid < 2048)   t32(h_fc_w, 2048, 512, hcT, 2048, 0, 0, bid - 1024, 16, tile);
    else if (bid < 3072)   t32(c_fc_w, 2048, 512, hcT + (size_t)512 * 2048, 2048, 0, 0, bid - 2048, 16, tile);
    else if (bid < 3328)   t32(dec_w, 512, 512, catT, 512, 0, 0, bid - 3072, 16, tile);
    else if (bid < 4352)   t32(beta_w, 512, 2048, catT + (size_t)512 * 512, 512, 0, 0, bid - 3328, 64, tile);
    else if (bid < 5376)   t32(w_hh, 512, 2048, catT + (size_t)2560 * 512, 512, 0, 1, bid - 4352, 64, tile);
    else if (bid < 9472)   t32(w_ih + (size_t)512 * 2048, 2048, 2048, combT, 2048, 0, 1, bid - 5376, 64, tile);
    else if (bid < 10496)  t32(w_ih, 512, 2048, wtopT, 512, 0, 1, bid - 9472, 64, tile);
    else if (bid < 15520)  t32(cls_w, 512, 10000, clsT, 512, 0, 0, bid - 10496, 314, tile);
    else {
        size_t i = (size_t)(bid - 15520) * 256 + threadIdx.x;
        if (i < (size_t)Tt * Bb * Ee) {
            int e = (int)(i % Ee);
            size_t r = i / Ee;
            int b = (int)(r % Bb);
            int t = (int)(r / Bb);
            int cap = caps[b * TMAX + t];
            embseq[i] = bfs(emb[(size_t)cap * Ee + e]);
        }
    }
}

// ---------------------------------------------------------------------------
extern "C" void kernel_launch(void* const* d_in, const int* in_sizes, int n_in,
                              void* d_out, int out_size, void* d_ws, size_t ws_size,
                              hipStream_t stream)
{
    const float* features = (const float*)d_in[0];
    const int* captions   = (const int*)d_in[1];
    const int* lengths    = (const int*)d_in[2];
    const float* emb      = (const float*)d_in[3];
    const float* h_fc_w   = (const float*)d_in[4];
    const float* h_fc_b   = (const float*)d_in[5];
    const float* c_fc_w   = (const float*)d_in[6];
    const float* c_fc_b   = (const float*)d_in[7];
    const float* enc_w    = (const float*)d_in[8];
    const float* enc_b    = (const float*)d_in[9];
    const float* dec_w    = (const float*)d_in[10];
    const float* dec_b    = (const float*)d_in[11];
    const float* att_w    = (const float*)d_in[12];
    const float* att_b    = (const float*)d_in[13];
    const float* beta_w   = (const float*)d_in[14];
    const float* beta_b   = (const float*)d_in[15];
    const float* w_ih     = (const float*)d_in[16];
    const float* b_ih     = (const float*)d_in[17];
    const float* w_hh     = (const float*)d_in[18];
    const float* b_hh     = (const float*)d_in[19];
    const float* cls_w    = (const float*)d_in[20];
    const float* cls_b    = (const float*)d_in[21];

    char* w = (char*)d_ws;
    auto alloc = [&](size_t bytes) {
        char* p = w;
        w += (bytes + 255) & ~(size_t)255;
        return p;
    };
    short* featb    = (short*)alloc((size_t)Bb * Pp * Dd * 2);
    short* att1b    = (short*)alloc((size_t)Bb * Pp * Aa * 2);
    short* encT     = (short*)alloc((size_t)Aa * Dd * 2);
    short* combT    = (short*)alloc((size_t)2048 * 2048 * 2); // w_ih bottom, qp rows
    short* wtopT    = (short*)alloc((size_t)2048 * 512 * 2);  // w_ih top, qp rows
    short* clsT     = (short*)alloc((size_t)NVP * Hh * 2);
    short* catT     = (short*)alloc((size_t)4608 * 512 * 2);  // [dec|beta|whh-qp]
    short* hcT      = (short*)alloc((size_t)1024 * Dd * 2);   // [h_fc;c_fc]
    short* embseq   = (short*)alloc((size_t)Tt * Bb * Ee * 2);
    short* meanb    = (short*)alloc((size_t)Bb * Dd * 2);
    short* eprec    = (short*)alloc((size_t)Tt * Bb * 2048 * 2);
    float* c_state  = (float*)alloc((size_t)Bb * Hh * 4);
    float* att2b    = (float*)alloc((size_t)Bb * Aa * 4);
    float* gatebuf  = (float*)alloc((size_t)Bb * Dd * 4);
    float* hpart    = (float*)alloc((size_t)Bb * 2048 * 4);
    short* xin      = (short*)alloc((size_t)Bb * 2048 * 2);   // awe only
    short* hb16     = (short*)alloc((size_t)Bb * Hh * 2);
    short* hnew_all = (short*)alloc((size_t)Tt * Bb * Hh * 2);

    float* y_out  = (float*)d_out;
    float* al_out = y_out + (size_t)Bb * Tt * Vv;

    // ---- precompute (5 launches) ----
    conv_mean_k<<<dim3(4, 128), 256, 0, stream>>>(features, featb, meanb);
    prep_k<<<dim3(20384), 256, 0, stream>>>(
        enc_w, h_fc_w, c_fc_w, dec_w, beta_w, w_ih, w_hh, cls_w, emb, captions,
        encT, hcT, catT, combT, wtopT, clsT, embseq);

    // h0/c0 GEMM: meanb @ hcT^T (EPI 6) -> hb16 + c_state
    gemm_k<128, 64, 64, 256, 2, 2, 6><<<dim3(16, 1), 256, 0, stream>>>(
        meanb, 2048, hcT, 2048, 2048,
        nullptr, c_state, nullptr, hb16, 0, h_fc_b, c_fc_b, nullptr);

    // att1 = features @ enc_w + enc_b (bf16), XCD-chunked 392-block grid
    gemm_k<128, 256, 64, 512, 2, 4, 0><<<dim3(392), 512, 0, stream>>>(
        featb, 2048, encT, 2048, 2048,
        nullptr, nullptr, att1b, nullptr, Aa, enc_b, nullptr, nullptr);

    // eprec = embseq @ wtopT^T (bf16, quad-permuted cols), all 19 steps
    gemm_k<128, 64, 64, 256, 2, 2, 1><<<dim3(32, 19), 256, 0, stream>>>(
        embseq, 512, wtopT, 512, 512,
        nullptr, nullptr, eprec, nullptr, 2048, nullptr, nullptr, nullptr);

    // ---- decode steps: 3 launches each ----
    for (int t = 0; t < Tt; ++t) {
        // K1: h @ [dec|beta|whh-qp], N=4608, K=512, 288 blocks
        gemm_k<32, 64, 64, 256, 2, 2, 4><<<dim3(288), 256, 0, stream>>>(
            hb16, 512, catT, 512, 512,
            att2b, gatebuf, (short*)hpart, nullptr, 0, dec_b, beta_b, nullptr);
        // K2: fused e/softmax/awe -> xin (+alpha output)
        att_awe_k<<<dim3(2, 128), 512, 0, stream>>>(
            att1b, att2b, att_w, att_b, featb, gatebuf, xin,
            al_out, lengths, t);
        // KB: gates GEMM (K=2048) + hpart + eprec + LSTM
        gates_lstm_k<<<dim3(256), 256, 0, stream>>>(
            xin, combT, eprec, hpart, b_ih, b_hh, c_state, hnew_all, hb16,
            lengths, t);
    }

    // deferred y: hnew_all[2432][512] @ clsT^T, XCD-chunked
    gemm_k<128, 64, 64, 256, 2, 2, 3><<<dim3(157 * Tt), 256, 0, stream>>>(
        hnew_all, 512, clsT, 512, 512,
        y_out, nullptr, nullptr, nullptr, 0, cls_b, nullptr, lengths);
}

// Round 11
// 1239.343 us; speedup vs baseline: 1.4017x; 1.0938x over previous
//
#include <hip/hip_runtime.h>
#include <cstdint>
#include <cstddef>

// ---------------------------------------------------------------------------
// Show-Attend-Tell decoder on MI355X (round 11).
// 3 launches per decode step (minimal: phases are truly dependent):
//   K1 gemm EPI4: h @ [dec | beta | W_hh(qp)]  (N=4608, K=512, 288 blocks)
//   K2 att_awe_k: e/relu/softmax + awe, ONE 1024-thr block per b (grid 128)
//   KB gates_lstm_k: awe @ W_ih_bot (K=2048) + hpart + eprec + LSTM
// All gemm_k instances now use the pipelined K-loop (2x-unrolled register
// double-buffer, 2 syncs/K-tile). y GEMM tiled 128x128 (NVP=10112=79*128).
// NOTES (post-mortems):
//  - r3: persistent coop kernel w/ agent-scope spin barrier = ~125us/barrier
//    + cache-invalidate storms. Do NOT revisit without hierarchical barrier.
//  - r4: inter-launch gap ~8us -> minimize launches on sequential chain.
//  - r6: matvec with [n][k] weights = uncoalesced, +45us/step.
//  - r7: prep_k section boundaries are ABSOLUTE block ids; grid must equal
//    the last boundary (now 20416). Re-derive on ANY section change.
//  - r9: per-b matvec fusion multiplies weight traffic by B/BM. Weight-
//    streaming ops MUST be m-tiled GEMMs.
// ---------------------------------------------------------------------------

#define DEV __device__ __forceinline__

typedef __attribute__((ext_vector_type(8))) short s16x8;
typedef __attribute__((ext_vector_type(4))) float f32x4;

constexpr int Bb = 128, Pp = 196, Dd = 2048, Aa = 512, Ee = 512, Hh = 512, Vv = 10000;
constexpr int Tt = 19, TMAX = 20;
constexpr int NVP = 10112;            // 79 * 128

DEV float fbs(short s) {
    union { uint32_t u; float f; } v;
    v.u = ((uint32_t)(uint16_t)s) << 16;
    return v.f;
}
DEV short bfs(float f) {
    union { float f; uint32_t u; } v;
    v.f = f;
    uint32_t u = v.u;
    uint32_t r = (u + 0x7FFFu + ((u >> 16) & 1u)) >> 16;  // RNE
    return (short)(uint16_t)r;
}
DEV void upk(uint32_t v, float& lo, float& hi) {
    union { uint32_t u; float f; } a, b;
    a.u = v << 16;
    b.u = v & 0xffff0000u;
    lo = a.f;
    hi = b.f;
}

// ---------------------------------------------------------------------------
// GEMM template. B stored [N][K]. LDS XOR-swizzled. Pipelined K-loop
// (register double-buffer; REQUIRES K % (2*BK) == 0).
// EPI: 0 = bf16 out + bias, XCD-chunked 1-D grid (att1; 392 blocks)
//      1 = bf16 out, no bias (eprec)
//      3 = deferred y with mask (1-D XCD-chunked grid 79*19)
//      4 = K1: 1-D grid 288; n<512 -> att2b f32 (+dec_b);
//          512<=n<2560 -> gatebuf sigmoid (+beta_b); else hpart f32 (no bias)
//      6 = h0c0: n<512 -> hb16 (+h_fc_b); else c_state (+c_fc_b)
// ---------------------------------------------------------------------------
template<int BM, int BN, int BK, int TH, int WR, int WC, int EPI>
__global__ __launch_bounds__(TH) void gemm_k(
    const short* __restrict__ Ag, int lda,
    const short* __restrict__ Bg, int ldb,
    int K,
    float* __restrict__ outF, float* __restrict__ outF2,
    short* __restrict__ outH, short* __restrict__ outH2,
    int ldo,
    const float* __restrict__ bias, const float* __restrict__ bias2,
    const int* __restrict__ lens)
{
    constexpr int NCH = BK / 8;
    constexpr int AU = NCH * BM, BU = NCH * BN;
    constexpr int APT = AU / TH, BPT = BU / TH;
    constexpr int WM = BM / WR, WN = BN / WC;
    constexpr int FM = WM / 16, FN = WN / 16;

    __shared__ __align__(16) short sA[AU * 8];
    __shared__ __align__(16) short sB[BU * 8];

    const int tid = threadIdx.x, lane = tid & 63, wid = tid >> 6;
    const int l15 = lane & 15, l4 = lane >> 4;

    int m0, n0, trow_ = 0;
    if constexpr (EPI == 0) {
        int task = (blockIdx.x & 7) * 49 + (blockIdx.x >> 3);   // 392 blocks
        m0 = (task >> 1) * BM;
        n0 = (task & 1) * BN;
    } else if constexpr (EPI == 3) {
        const int nwg = (int)gridDim.x;                         // 79*19
        const int qq = nwg >> 3, rr = nwg & 7;
        int xcd = (int)blockIdx.x & 7, idx = (int)blockIdx.x >> 3;
        int task = (xcd < rr) ? xcd * (qq + 1) + idx
                              : rr * (qq + 1) + (xcd - rr) * qq + idx;
        int npanel = task / Tt;
        trow_ = task - npanel * Tt;
        m0 = trow_ * BM;
        n0 = npanel * BN;
    } else if constexpr (EPI == 4) {
        m0 = ((int)blockIdx.x & 3) * BM;
        n0 = ((int)blockIdx.x >> 2) * BN;
    } else {
        m0 = blockIdx.y * BM;
        n0 = blockIdx.x * BN;
    }
    const int wr = wid / WC, wc = wid % WC;

    f32x4 acc[FM][FN];
    #pragma unroll
    for (int i = 0; i < FM; ++i)
        #pragma unroll
        for (int j = 0; j < FN; ++j) acc[i][j] = {0.f, 0.f, 0.f, 0.f};

    s16x8 ra[APT], rb[BPT], ra2[APT], rb2[BPT];

    auto gload = [&](int kt, s16x8 (&pa)[APT], s16x8 (&pb)[BPT]) {
        #pragma unroll
        for (int i = 0; i < APT; ++i) {
            int q2 = tid + TH * i;
            int r2 = q2 / NCH, ch = q2 % NCH;
            pa[i] = *(const s16x8*)(Ag + (size_t)(m0 + r2) * lda + kt + ch * 8);
        }
        #pragma unroll
        for (int i = 0; i < BPT; ++i) {
            int q2 = tid + TH * i;
            int r2 = q2 / NCH, ch = q2 % NCH;
            pb[i] = *(const s16x8*)(Bg + (size_t)(n0 + r2) * ldb + kt + ch * 8);
        }
    };
    auto sstore = [&](s16x8 (&pa)[APT], s16x8 (&pb)[BPT]) {
        #pragma unroll
        for (int i = 0; i < APT; ++i) {
            int q2 = tid + TH * i;
            int r2 = q2 / NCH, ch = q2 % NCH;
            *(s16x8*)(sA + (r2 * NCH + (ch ^ (r2 & 7))) * 8) = pa[i];
        }
        #pragma unroll
        for (int i = 0; i < BPT; ++i) {
            int q2 = tid + TH * i;
            int r2 = q2 / NCH, ch = q2 % NCH;
            *(s16x8*)(sB + (r2 * NCH + (ch ^ (r2 & 7))) * 8) = pb[i];
        }
    };
    auto domfma = [&]() {
        #pragma unroll
        for (int ks = 0; ks < BK / 32; ++ks) {
            s16x8 af[FM], bf[FN];
            #pragma unroll
            for (int fm = 0; fm < FM; ++fm) {
                int rr2 = wr * WM + fm * 16 + l15, cc = ks * 4 + l4;
                af[fm] = *(const s16x8*)&sA[(rr2 * NCH + (cc ^ (rr2 & 7))) * 8];
            }
            #pragma unroll
            for (int fn = 0; fn < FN; ++fn) {
                int rr2 = wc * WN + fn * 16 + l15, cc = ks * 4 + l4;
                bf[fn] = *(const s16x8*)&sB[(rr2 * NCH + (cc ^ (rr2 & 7))) * 8];
            }
            #pragma unroll
            for (int fm = 0; fm < FM; ++fm)
                #pragma unroll
                for (int fn = 0; fn < FN; ++fn)
                    acc[fm][fn] = __builtin_amdgcn_mfma_f32_16x16x32_bf16(af[fm], bf[fn], acc[fm][fn], 0, 0, 0);
        }
    };

    gload(0, ra, rb);
    #pragma unroll 1
    for (int kt = 0; kt < K; kt += 2 * BK) {
        __syncthreads();
        sstore(ra, rb);
        __syncthreads();
        gload(kt + BK, ra2, rb2);          // kt+BK < K always (K % 2BK == 0)
        domfma();
        __syncthreads();
        sstore(ra2, rb2);
        __syncthreads();
        if (kt + 2 * BK < K) gload(kt + 2 * BK, ra, rb);
        domfma();
    }

    #pragma unroll
    for (int fm = 0; fm < FM; ++fm)
        #pragma unroll
        for (int fn = 0; fn < FN; ++fn)
            #pragma unroll
            for (int r2 = 0; r2 < 4; ++r2) {
                int ml = wr * WM + fm * 16 + l4 * 4 + r2;
                int nl = wc * WN + fn * 16 + l15;
                int m = m0 + ml, n = n0 + nl;
                float v = acc[fm][fn][r2];
                if constexpr (EPI == 0) {
                    outH[(size_t)m * ldo + n] = bfs(v + bias[n]);
                } else if constexpr (EPI == 1) {
                    outH[(size_t)m * ldo + n] = bfs(v);
                } else if constexpr (EPI == 3) {
                    if (n < Vv) {
                        bool mk = trow_ < lens[ml] - 1;
                        outF[((size_t)ml * Tt + trow_) * Vv + n] = mk ? (v + bias[n]) : 0.f;
                    }
                } else if constexpr (EPI == 4) {
                    if (n < 512) outF[(size_t)m * Aa + n] = v + bias[n];
                    else if (n < 2560)
                        outF2[(size_t)m * Dd + (n - 512)] =
                            1.f / (1.f + expf(-(v + bias2[n - 512])));
                    else
                        ((float*)outH)[(size_t)m * 2048 + (n - 2560)] = v;  // hpart
                } else if constexpr (EPI == 6) {
                    if (n < 512) {
                        outH2[(size_t)m * 512 + n] = bfs(v + bias[n]);      // hb16
                    } else {
                        outF2[(size_t)m * 512 + (n - 512)] = v + bias2[n - 512]; // c_state
                    }
                }
            }
}

// ---------------------------------------------------------------------------
// K2: fused e = relu(att1+att2)@att_w + att_b -> softmax -> alpha -> awe.
// ONE block per b, 1024 threads (16 waves). att1 row read once per b.
// ---------------------------------------------------------------------------
__global__ __launch_bounds__(1024) void att_awe_k(
    const short* __restrict__ att1b, const float* __restrict__ att2b,
    const float* __restrict__ att_w, const float* __restrict__ att_b,
    const short* __restrict__ featb, const float* __restrict__ gatebuf,
    short* __restrict__ xin, float* __restrict__ al_out,
    const int* __restrict__ lens, int t)
{
    const int b = blockIdx.x;
    const int tid = threadIdx.x, lane = tid & 63, wid = tid >> 6;   // 16 waves
    __shared__ float se[224];
    __shared__ float sred[256];
    __shared__ float sal[224];

    float aw[8], a2[8];
    #pragma unroll
    for (int j = 0; j < 8; ++j) {
        aw[j] = att_w[lane * 8 + j];
        a2[j] = att2b[b * 512 + lane * 8 + j];
    }
    float ab = att_b[0];
    for (int p = wid; p < Pp; p += 16) {
        s16x8 row = *(const s16x8*)&att1b[((size_t)b * Pp + p) * 512 + lane * 8];
        float s = 0.f;
        #pragma unroll
        for (int j = 0; j < 8; ++j) {
            float v = fbs(row[j]) + a2[j];
            v = v > 0.f ? v : 0.f;
            s += v * aw[j];
        }
        #pragma unroll
        for (int m = 32; m; m >>= 1) s += __shfl_xor(s, m);
        if (lane == 0) se[p] = s + ab;
    }
    __syncthreads();
    float e = 0.f, ex = 0.f;
    if (tid < 256) {
        e = (tid < Pp) ? se[tid] : -3.0e38f;
        sred[tid] = e;
    }
    __syncthreads();
    for (int st = 128; st > 0; st >>= 1) {
        if (tid < st) sred[tid] = fmaxf(sred[tid], sred[tid + st]);
        __syncthreads();
    }
    float mx = sred[0];
    __syncthreads();
    if (tid < 256) {
        ex = (tid < Pp) ? expf(e - mx) : 0.f;
        sred[tid] = ex;
    }
    __syncthreads();
    for (int st = 128; st > 0; st >>= 1) {
        if (tid < st) sred[tid] += sred[tid + st];
        __syncthreads();
    }
    float inv = 1.f / sred[0];
    if (tid < Pp) {
        float al = ex * inv;
        sal[tid] = al;
        float mf = (t < lens[b] - 1) ? 1.f : 0.f;
        al_out[((size_t)b * Tt + t) * Pp + tid] = al * mf;
    }
    __syncthreads();
    // awe: 2 cols per thread over all 2048
    int d0 = tid * 2;
    const short* f = featb + (size_t)b * Pp * Dd + d0;
    float s0 = 0.f, s1 = 0.f;
    #pragma unroll 4
    for (int p = 0; p < Pp; ++p) {
        uint32_t v = *(const uint32_t*)(f + (size_t)p * Dd);
        float lo, hi;
        upk(v, lo, hi);
        float al = sal[p];
        s0 += al * lo;
        s1 += al * hi;
    }
    float2 g = *(const float2*)&gatebuf[b * 2048 + d0];
    uint32_t o = ((uint32_t)(uint16_t)bfs(g.y * s1) << 16) | (uint16_t)bfs(g.x * s0);
    *(uint32_t*)(xin + (size_t)b * 2048 + d0) = o;
}

// ---------------------------------------------------------------------------
// KB: gates = xin(awe) @ combT (quad-perm, K=2048) + hpart + eprec + biases
//     -> LSTM update. grid 256: m0=(bid&3)*32, n0=(bid>>2)*32.
// Pipelined k-loop: 2x-unrolled register double-buffer.
// ---------------------------------------------------------------------------
__global__ __launch_bounds__(256) void gates_lstm_k(
    const short* __restrict__ xin, const short* __restrict__ combT,
    const short* __restrict__ eprec, const float* __restrict__ hpart,
    const float* __restrict__ b_ih, const float* __restrict__ b_hh,
    float* __restrict__ c_state, short* __restrict__ hnew_all,
    short* __restrict__ hb16, const int* __restrict__ lens, int t)
{
    constexpr int BM = 32, BN = 32, BK = 128, K = 2048;  // 2048 = 16 * 128
    constexpr int NCH = BK / 8;                          // 16
    constexpr int AU = NCH * BM;                         // 512 16B-units
    __shared__ __align__(16) short sA[AU * 8];
    __shared__ __align__(16) short sB[AU * 8];

    const int m0 = ((int)blockIdx.x & 3) * BM, n0 = ((int)blockIdx.x >> 2) * BN;
    const int tid = threadIdx.x, lane = tid & 63, wid = tid >> 6;
    const int l15 = lane & 15, l4 = lane >> 4;
    const int wr = wid >> 1, wc = wid & 1;               // WR=2, WC=2

    f32x4 acc = {0.f, 0.f, 0.f, 0.f};
    const int r2 = tid / NCH, ch0 = tid % NCH;           // rows r2, r2+16
    const short* Abase = xin + (size_t)(m0 + r2) * 2048 + ch0 * 8;
    const short* Bbase = combT + (size_t)(n0 + r2) * 2048 + ch0 * 8;
    const size_t rowadv = (size_t)16 * 2048;

    s16x8 raA0, raA1, rbA0, rbA1, raB0, raB1, rbB0, rbB1;

    auto loadA = [&](int kt, s16x8& a0, s16x8& a1, s16x8& b0, s16x8& b1) {
        a0 = *(const s16x8*)(Abase + kt);
        a1 = *(const s16x8*)(Abase + rowadv + kt);
        b0 = *(const s16x8*)(Bbase + kt);
        b1 = *(const s16x8*)(Bbase + rowadv + kt);
    };
    const int sl0 = ((r2) * NCH + (ch0 ^ (r2 & 7))) * 8;
    const int sl1 = ((r2 + 16) * NCH + (ch0 ^ ((r2 + 16) & 7))) * 8;
    auto storeS = [&](s16x8& a0, s16x8& a1, s16x8& b0, s16x8& b1) {
        *(s16x8*)(sA + sl0) = a0;
        *(s16x8*)(sA + sl1) = a1;
        *(s16x8*)(sB + sl0) = b0;
        *(s16x8*)(sB + sl1) = b1;
    };
    const int rrA = wr * 16 + l15, rrB = wc * 16 + l15;
    auto mfmaS = [&]() {
        #pragma unroll
        for (int ks = 0; ks < BK / 32; ++ks) {
            int cc = ks * 4 + l4;
            s16x8 af = *(const s16x8*)&sA[(rrA * NCH + (cc ^ (rrA & 7))) * 8];
            s16x8 bf = *(const s16x8*)&sB[(rrB * NCH + (cc ^ (rrB & 7))) * 8];
            acc = __builtin_amdgcn_mfma_f32_16x16x32_bf16(af, bf, acc, 0, 0, 0);
        }
    };

    loadA(0, raA0, raA1, rbA0, rbA1);
    #pragma unroll 1
    for (int kt = 0; kt < K; kt += 2 * BK) {
        __syncthreads();
        storeS(raA0, raA1, rbA0, rbA1);
        __syncthreads();
        if (kt + BK < K) loadA(kt + BK, raB0, raB1, rbB0, rbB1);
        mfmaS();
        __syncthreads();
        storeS(raB0, raB1, rbB0, rbB1);
        __syncthreads();
        if (kt + 2 * BK < K) loadA(kt + 2 * BK, raA0, raA1, rbA0, rbA1);
        mfmaS();
    }

    // LSTM epilogue via LDS round-trip (quad-permuted cols: q = n0/4 + jl)
    __syncthreads();
    float* sE = (float*)sA;
    #pragma unroll
    for (int r = 0; r < 4; ++r) {
        int ml = wr * 16 + l4 * 4 + r, nl = wc * 16 + l15;
        sE[ml * 32 + nl] = acc[r];
    }
    __syncthreads();
    int bl = tid >> 3, jl = tid & 7;
    int b = m0 + bl, q = (n0 >> 2) + jl;
    f32x4 ge = *(const f32x4*)&sE[bl * 32 + jl * 4];
    f32x4 hp = *(const f32x4*)&hpart[(size_t)b * 2048 + n0 + jl * 4];
    short4 ep = *(const short4*)&eprec[((size_t)t * 128 + b) * 2048 + n0 + jl * 4];
    float gi = ge[0] + hp[0] + fbs(ep.x) + b_ih[q]        + b_hh[q];
    float gf = ge[1] + hp[1] + fbs(ep.y) + b_ih[512 + q]  + b_hh[512 + q];
    float gg = ge[2] + hp[2] + fbs(ep.z) + b_ih[1024 + q] + b_hh[1024 + q];
    float go = ge[3] + hp[3] + fbs(ep.w) + b_ih[1536 + q] + b_hh[1536 + q];
    float si = 1.f / (1.f + expf(-gi));
    float sf = 1.f / (1.f + expf(-gf));
    float so = 1.f / (1.f + expf(-go));
    float tg = tanhf(gg);
    int sidx = b * 512 + q;
    float cn = sf * c_state[sidx] + si * tg;
    float hn = so * tanhf(cn);
    hnew_all[((size_t)t * 128 + b) * 512 + q] = bfs(hn);
    if (t < lens[b] - 1) {
        c_state[sidx] = cn;
        hb16[sidx] = bfs(hn);
    }
}

// ---------------------------------------------------------------------------
// conv/mean: features fp32 -> bf16, bf16 mean over P.  grid (4,128), 2 d/thr.
// ---------------------------------------------------------------------------
__global__ __launch_bounds__(256) void conv_mean_k(
    const float* __restrict__ feat, short* __restrict__ featb, short* __restrict__ meanb)
{
    int b = blockIdx.y;
    int d = (blockIdx.x * 256 + threadIdx.x) * 2;
    const float* f = feat + (size_t)b * Pp * Dd + d;
    short* o = featb + (size_t)b * Pp * Dd + d;
    float s0 = 0.f, s1 = 0.f;
    #pragma unroll 4
    for (int p = 0; p < Pp; ++p) {
        float2 v = *(const float2*)(f + (size_t)p * Dd);
        s0 += v.x; s1 += v.y;
        uint32_t ov = ((uint32_t)(uint16_t)bfs(v.y) << 16) | (uint16_t)bfs(v.x);
        *(uint32_t*)(o + (size_t)p * Dd) = ov;
    }
    const float inv = 1.f / 196.f;
    uint32_t mv = ((uint32_t)(uint16_t)bfs(s1 * inv) << 16) | (uint16_t)bfs(s0 * inv);
    *(uint32_t*)(meanb + (size_t)b * Dd + d) = mv;
}

// ---------------------------------------------------------------------------
// prep_k: weight transposes + embedding gather in ONE launch.
// Section boundaries (ABSOLUTE block ids; grid MUST be 20416):
//   [0,1024) enc | [1024,2048) h_fc | [2048,3072) c_fc | [3072,3328) dec
//   [3328,4352) beta | [4352,5376) w_hh-qp | [5376,9472) w_ih-bot
//   [9472,10496) w_ih-top | [10496,15552) cls (gx=316) | [15552,20416) embg
// ---------------------------------------------------------------------------
DEV void t32(const float* __restrict__ src, int R, int C,
             short* __restrict__ dst, int ds, int off, int perm,
             int local, int gx, float (*tile)[33])
{
    int x = local % gx, y = local / gx;
    int c0 = x * 32, r0 = y * 32;
    int tx = threadIdx.x & 31, ty = threadIdx.x >> 5;
    #pragma unroll
    for (int i = 0; i < 4; ++i) {
        int r = r0 + ty + i * 8, c = c0 + tx;
        tile[ty + i * 8][tx] = (r < R && c < C) ? src[(size_t)r * C + c] : 0.f;
    }
    __syncthreads();
    #pragma unroll
    for (int i = 0; i < 4; ++i) {
        int cc = c0 + ty + i * 8, rr = r0 + tx;
        if (rr < R) {
            int drow = perm ? ((cc & 511) * 4 + (cc >> 9)) : cc;
            dst[(size_t)drow * ds + off + rr] = bfs(tile[tx][ty + i * 8]);
        }
    }
}

__global__ __launch_bounds__(256) void prep_k(
    const float* __restrict__ enc_w, const float* __restrict__ h_fc_w,
    const float* __restrict__ c_fc_w, const float* __restrict__ dec_w,
    const float* __restrict__ beta_w, const float* __restrict__ w_ih,
    const float* __restrict__ w_hh, const float* __restrict__ cls_w,
    const float* __restrict__ emb, const int* __restrict__ caps,
    short* __restrict__ encT, short* __restrict__ hcT, short* __restrict__ catT,
    short* __restrict__ combT, short* __restrict__ wtopT, short* __restrict__ clsT,
    short* __restrict__ embseq)
{
    __shared__ float tile[32][33];
    int bid = blockIdx.x;
    if (bid < 1024)        t32(enc_w, 2048, 512, encT, 2048, 0, 0, bid, 16, tile);
    else if (bid < 2048)   t32(h_fc_w, 2048, 512, hcT, 2048, 0, 0, bid - 1024, 16, tile);
    else if (bid < 3072)   t32(c_fc_w, 2048, 512, hcT + (size_t)512 * 2048, 2048, 0, 0, bid - 2048, 16, tile);
    else if (bid < 3328)   t32(dec_w, 512, 512, catT, 512, 0, 0, bid - 3072, 16, tile);
    else if (bid < 4352)   t32(beta_w, 512, 2048, catT + (size_t)512 * 512, 512, 0, 0, bid - 3328, 64, tile);
    else if (bid < 5376)   t32(w_hh, 512, 2048, catT + (size_t)2560 * 512, 512, 0, 1, bid - 4352, 64, tile);
    else if (bid < 9472)   t32(w_ih + (size_t)512 * 2048, 2048, 2048, combT, 2048, 0, 1, bid - 5376, 64, tile);
    else if (bid < 10496)  t32(w_ih, 512, 2048, wtopT, 512, 0, 1, bid - 9472, 64, tile);
    else if (bid < 15552)  t32(cls_w, 512, 10000, clsT, 512, 0, 0, bid - 10496, 316, tile);
    else {
        size_t i = (size_t)(bid - 15552) * 256 + threadIdx.x;
        if (i < (size_t)Tt * Bb * Ee) {
            int e = (int)(i % Ee);
            size_t r = i / Ee;
            int b = (int)(r % Bb);
            int t = (int)(r / Bb);
            int cap = caps[b * TMAX + t];
            embseq[i] = bfs(emb[(size_t)cap * Ee + e]);
        }
    }
}

// ---------------------------------------------------------------------------
extern "C" void kernel_launch(void* const* d_in, const int* in_sizes, int n_in,
                              void* d_out, int out_size, void* d_ws, size_t ws_size,
                              hipStream_t stream)
{
    const float* features = (const float*)d_in[0];
    const int* captions   = (const int*)d_in[1];
    const int* lengths    = (const int*)d_in[2];
    const float* emb      = (const float*)d_in[3];
    const float* h_fc_w   = (const float*)d_in[4];
    const float* h_fc_b   = (const float*)d_in[5];
    const float* c_fc_w   = (const float*)d_in[6];
    const float* c_fc_b   = (const float*)d_in[7];
    const float* enc_w    = (const float*)d_in[8];
    const float* enc_b    = (const float*)d_in[9];
    const float* dec_w    = (const float*)d_in[10];
    const float* dec_b    = (const float*)d_in[11];
    const float* att_w    = (const float*)d_in[12];
    const float* att_b    = (const float*)d_in[13];
    const float* beta_w   = (const float*)d_in[14];
    const float* beta_b   = (const float*)d_in[15];
    const float* w_ih     = (const float*)d_in[16];
    const float* b_ih     = (const float*)d_in[17];
    const float* w_hh     = (const float*)d_in[18];
    const float* b_hh     = (const float*)d_in[19];
    const float* cls_w    = (const float*)d_in[20];
    const float* cls_b    = (const float*)d_in[21];

    char* w = (char*)d_ws;
    auto alloc = [&](size_t bytes) {
        char* p = w;
        w += (bytes + 255) & ~(size_t)255;
        return p;
    };
    short* featb    = (short*)alloc((size_t)Bb * Pp * Dd * 2);
    short* att1b    = (short*)alloc((size_t)Bb * Pp * Aa * 2);
    short* encT     = (short*)alloc((size_t)Aa * Dd * 2);
    short* combT    = (short*)alloc((size_t)2048 * 2048 * 2); // w_ih bottom, qp rows
    short* wtopT    = (short*)alloc((size_t)2048 * 512 * 2);  // w_ih top, qp rows
    short* clsT     = (short*)alloc((size_t)NVP * Hh * 2);
    short* catT     = (short*)alloc((size_t)4608 * 512 * 2);  // [dec|beta|whh-qp]
    short* hcT      = (short*)alloc((size_t)1024 * Dd * 2);   // [h_fc;c_fc]
    short* embseq   = (short*)alloc((size_t)Tt * Bb * Ee * 2);
    short* meanb    = (short*)alloc((size_t)Bb * Dd * 2);
    short* eprec    = (short*)alloc((size_t)Tt * Bb * 2048 * 2);
    float* c_state  = (float*)alloc((size_t)Bb * Hh * 4);
    float* att2b    = (float*)alloc((size_t)Bb * Aa * 4);
    float* gatebuf  = (float*)alloc((size_t)Bb * Dd * 4);
    float* hpart    = (float*)alloc((size_t)Bb * 2048 * 4);
    short* xin      = (short*)alloc((size_t)Bb * 2048 * 2);   // awe only
    short* hb16     = (short*)alloc((size_t)Bb * Hh * 2);
    short* hnew_all = (short*)alloc((size_t)Tt * Bb * Hh * 2);

    float* y_out  = (float*)d_out;
    float* al_out = y_out + (size_t)Bb * Tt * Vv;

    // ---- precompute (5 launches) ----
    conv_mean_k<<<dim3(4, 128), 256, 0, stream>>>(features, featb, meanb);
    prep_k<<<dim3(20416), 256, 0, stream>>>(
        enc_w, h_fc_w, c_fc_w, dec_w, beta_w, w_ih, w_hh, cls_w, emb, captions,
        encT, hcT, catT, combT, wtopT, clsT, embseq);

    // h0/c0 GEMM: meanb @ hcT^T (EPI 6) -> hb16 + c_state
    gemm_k<128, 64, 64, 256, 2, 2, 6><<<dim3(16, 1), 256, 0, stream>>>(
        meanb, 2048, hcT, 2048, 2048,
        nullptr, c_state, nullptr, hb16, 0, h_fc_b, c_fc_b, nullptr);

    // att1 = features @ enc_w + enc_b (bf16), XCD-chunked 392-block grid
    gemm_k<128, 256, 64, 512, 2, 4, 0><<<dim3(392), 512, 0, stream>>>(
        featb, 2048, encT, 2048, 2048,
        nullptr, nullptr, att1b, nullptr, Aa, enc_b, nullptr, nullptr);

    // eprec = embseq @ wtopT^T (bf16, quad-permuted cols), all 19 steps
    gemm_k<128, 64, 64, 256, 2, 2, 1><<<dim3(32, 19), 256, 0, stream>>>(
        embseq, 512, wtopT, 512, 512,
        nullptr, nullptr, eprec, nullptr, 2048, nullptr, nullptr, nullptr);

    // ---- decode steps: 3 launches each ----
    for (int t = 0; t < Tt; ++t) {
        // K1: h @ [dec|beta|whh-qp], N=4608, K=512, 288 blocks
        gemm_k<32, 64, 64, 256, 2, 2, 4><<<dim3(288), 256, 0, stream>>>(
            hb16, 512, catT, 512, 512,
            att2b, gatebuf, (short*)hpart, nullptr, 0, dec_b, beta_b, nullptr);
        // K2: fused e/softmax/awe -> xin (+alpha output), 1 block/b
        att_awe_k<<<dim3(128), 1024, 0, stream>>>(
            att1b, att2b, att_w, att_b, featb, gatebuf, xin,
            al_out, lengths, t);
        // KB: gates GEMM (K=2048) + hpart + eprec + LSTM
        gates_lstm_k<<<dim3(256), 256, 0, stream>>>(
            xin, combT, eprec, hpart, b_ih, b_hh, c_state, hnew_all, hb16,
            lengths, t);
    }

    // deferred y: hnew_all[2432][512] @ clsT^T (128x128 tiles), XCD-chunked
    gemm_k<128, 128, 64, 256, 2, 2, 3><<<dim3(79 * Tt), 256, 0, stream>>>(
        hnew_all, 512, clsT, 512, 512,
        y_out, nullptr, nullptr, nullptr, 0, cls_b, nullptr, lengths);
}

// Round 12
// 1220.999 us; speedup vs baseline: 1.4228x; 1.0150x over previous
//
#include <hip/hip_runtime.h>
#include <cstdint>
#include <cstddef>

// ---------------------------------------------------------------------------
// Show-Attend-Tell decoder on MI355X (round 12).
// 3 launches per decode step (minimal: phases are truly dependent):
//   K1 gemm EPI4: h @ [dec | beta | W_hh(qp)]  (N=4608, K=512, BK=128)
//   K2 att_awe_k: e/relu/softmax(wave-0 shuffle) + awe, 1024-thr block per b
//   KB gates_lstm_k: awe @ W_ih_bot (K=2048) + hpart + eprec + LSTM
// NOTES (post-mortems):
//  - r3: persistent coop kernel w/ agent-scope spin barrier = ~125us/barrier
//    + cache-invalidate storms. Do NOT revisit without hierarchical barrier.
//  - r4: inter-launch gap ~6-8us -> minimize launches on sequential chain.
//  - r6: matvec with [n][k] weights = uncoalesced, +45us/step.
//  - r7: prep_k section boundaries are ABSOLUTE block ids; grid must equal
//    the last boundary (20416). Re-derive on ANY section change.
//  - r9: per-b matvec fusion multiplies weight traffic by B/BM. Weight-
//    streaming ops MUST be m-tiled GEMMs.
// ---------------------------------------------------------------------------

#define DEV __device__ __forceinline__

typedef __attribute__((ext_vector_type(8))) short s16x8;
typedef __attribute__((ext_vector_type(4))) float f32x4;

constexpr int Bb = 128, Pp = 196, Dd = 2048, Aa = 512, Ee = 512, Hh = 512, Vv = 10000;
constexpr int Tt = 19, TMAX = 20;
constexpr int NVP = 10112;            // 79 * 128

DEV float fbs(short s) {
    union { uint32_t u; float f; } v;
    v.u = ((uint32_t)(uint16_t)s) << 16;
    return v.f;
}
DEV short bfs(float f) {
    union { float f; uint32_t u; } v;
    v.f = f;
    uint32_t u = v.u;
    uint32_t r = (u + 0x7FFFu + ((u >> 16) & 1u)) >> 16;  // RNE
    return (short)(uint16_t)r;
}
DEV void upk(uint32_t v, float& lo, float& hi) {
    union { uint32_t u; float f; } a, b;
    a.u = v << 16;
    b.u = v & 0xffff0000u;
    lo = a.f;
    hi = b.f;
}

// ---------------------------------------------------------------------------
// GEMM template. B stored [N][K]. LDS XOR-swizzled. Pipelined K-loop
// (register double-buffer; REQUIRES K % (2*BK) == 0).
// EPI: 0 = bf16 out + bias, XCD-chunked 1-D grid (att1; 392 blocks)
//      1 = bf16 out, no bias (eprec)
//      3 = deferred y with mask (1-D XCD-chunked grid 79*19)
//      4 = K1: 1-D grid 288; n<512 -> att2b f32 (+dec_b);
//          512<=n<2560 -> gatebuf sigmoid (+beta_b); else hpart f32 (no bias)
//      6 = h0c0: n<512 -> hb16 (+h_fc_b); else c_state (+c_fc_b)
// ---------------------------------------------------------------------------
template<int BM, int BN, int BK, int TH, int WR, int WC, int EPI>
__global__ __launch_bounds__(TH) void gemm_k(
    const short* __restrict__ Ag, int lda,
    const short* __restrict__ Bg, int ldb,
    int K,
    float* __restrict__ outF, float* __restrict__ outF2,
    short* __restrict__ outH, short* __restrict__ outH2,
    int ldo,
    const float* __restrict__ bias, const float* __restrict__ bias2,
    const int* __restrict__ lens)
{
    constexpr int NCH = BK / 8;
    constexpr int AU = NCH * BM, BU = NCH * BN;
    constexpr int APT = AU / TH, BPT = BU / TH;
    constexpr int WM = BM / WR, WN = BN / WC;
    constexpr int FM = WM / 16, FN = WN / 16;

    __shared__ __align__(16) short sA[AU * 8];
    __shared__ __align__(16) short sB[BU * 8];

    const int tid = threadIdx.x, lane = tid & 63, wid = tid >> 6;
    const int l15 = lane & 15, l4 = lane >> 4;

    int m0, n0, trow_ = 0;
    if constexpr (EPI == 0) {
        int task = (blockIdx.x & 7) * 49 + (blockIdx.x >> 3);   // 392 blocks
        m0 = (task >> 1) * BM;
        n0 = (task & 1) * BN;
    } else if constexpr (EPI == 3) {
        const int nwg = (int)gridDim.x;                         // 79*19
        const int qq = nwg >> 3, rr = nwg & 7;
        int xcd = (int)blockIdx.x & 7, idx = (int)blockIdx.x >> 3;
        int task = (xcd < rr) ? xcd * (qq + 1) + idx
                              : rr * (qq + 1) + (xcd - rr) * qq + idx;
        int npanel = task / Tt;
        trow_ = task - npanel * Tt;
        m0 = trow_ * BM;
        n0 = npanel * BN;
    } else if constexpr (EPI == 4) {
        m0 = ((int)blockIdx.x & 3) * BM;
        n0 = ((int)blockIdx.x >> 2) * BN;
    } else {
        m0 = blockIdx.y * BM;
        n0 = blockIdx.x * BN;
    }
    const int wr = wid / WC, wc = wid % WC;

    f32x4 acc[FM][FN];
    #pragma unroll
    for (int i = 0; i < FM; ++i)
        #pragma unroll
        for (int j = 0; j < FN; ++j) acc[i][j] = {0.f, 0.f, 0.f, 0.f};

    s16x8 ra[APT], rb[BPT], ra2[APT], rb2[BPT];

    auto gload = [&](int kt, s16x8 (&pa)[APT], s16x8 (&pb)[BPT]) {
        #pragma unroll
        for (int i = 0; i < APT; ++i) {
            int q2 = tid + TH * i;
            int r2 = q2 / NCH, ch = q2 % NCH;
            pa[i] = *(const s16x8*)(Ag + (size_t)(m0 + r2) * lda + kt + ch * 8);
        }
        #pragma unroll
        for (int i = 0; i < BPT; ++i) {
            int q2 = tid + TH * i;
            int r2 = q2 / NCH, ch = q2 % NCH;
            pb[i] = *(const s16x8*)(Bg + (size_t)(n0 + r2) * ldb + kt + ch * 8);
        }
    };
    auto sstore = [&](s16x8 (&pa)[APT], s16x8 (&pb)[BPT]) {
        #pragma unroll
        for (int i = 0; i < APT; ++i) {
            int q2 = tid + TH * i;
            int r2 = q2 / NCH, ch = q2 % NCH;
            *(s16x8*)(sA + (r2 * NCH + (ch ^ (r2 & 7))) * 8) = pa[i];
        }
        #pragma unroll
        for (int i = 0; i < BPT; ++i) {
            int q2 = tid + TH * i;
            int r2 = q2 / NCH, ch = q2 % NCH;
            *(s16x8*)(sB + (r2 * NCH + (ch ^ (r2 & 7))) * 8) = pb[i];
        }
    };
    auto domfma = [&]() {
        #pragma unroll
        for (int ks = 0; ks < BK / 32; ++ks) {
            s16x8 af[FM], bf[FN];
            #pragma unroll
            for (int fm = 0; fm < FM; ++fm) {
                int rr2 = wr * WM + fm * 16 + l15, cc = ks * 4 + l4;
                af[fm] = *(const s16x8*)&sA[(rr2 * NCH + (cc ^ (rr2 & 7))) * 8];
            }
            #pragma unroll
            for (int fn = 0; fn < FN; ++fn) {
                int rr2 = wc * WN + fn * 16 + l15, cc = ks * 4 + l4;
                bf[fn] = *(const s16x8*)&sB[(rr2 * NCH + (cc ^ (rr2 & 7))) * 8];
            }
            #pragma unroll
            for (int fm = 0; fm < FM; ++fm)
                #pragma unroll
                for (int fn = 0; fn < FN; ++fn)
                    acc[fm][fn] = __builtin_amdgcn_mfma_f32_16x16x32_bf16(af[fm], bf[fn], acc[fm][fn], 0, 0, 0);
        }
    };

    gload(0, ra, rb);
    #pragma unroll 1
    for (int kt = 0; kt < K; kt += 2 * BK) {
        __syncthreads();
        sstore(ra, rb);
        __syncthreads();
        gload(kt + BK, ra2, rb2);          // kt+BK < K always (K % 2BK == 0)
        domfma();
        __syncthreads();
        sstore(ra2, rb2);
        __syncthreads();
        if (kt + 2 * BK < K) gload(kt + 2 * BK, ra, rb);
        domfma();
    }

    #pragma unroll
    for (int fm = 0; fm < FM; ++fm)
        #pragma unroll
        for (int fn = 0; fn < FN; ++fn)
            #pragma unroll
            for (int r2 = 0; r2 < 4; ++r2) {
                int ml = wr * WM + fm * 16 + l4 * 4 + r2;
                int nl = wc * WN + fn * 16 + l15;
                int m = m0 + ml, n = n0 + nl;
                float v = acc[fm][fn][r2];
                if constexpr (EPI == 0) {
                    outH[(size_t)m * ldo + n] = bfs(v + bias[n]);
                } else if constexpr (EPI == 1) {
                    outH[(size_t)m * ldo + n] = bfs(v);
                } else if constexpr (EPI == 3) {
                    if (n < Vv) {
                        bool mk = trow_ < lens[ml] - 1;
                        outF[((size_t)ml * Tt + trow_) * Vv + n] = mk ? (v + bias[n]) : 0.f;
                    }
                } else if constexpr (EPI == 4) {
                    if (n < 512) outF[(size_t)m * Aa + n] = v + bias[n];
                    else if (n < 2560)
                        outF2[(size_t)m * Dd + (n - 512)] =
                            1.f / (1.f + expf(-(v + bias2[n - 512])));
                    else
                        ((float*)outH)[(size_t)m * 2048 + (n - 2560)] = v;  // hpart
                } else if constexpr (EPI == 6) {
                    if (n < 512) {
                        outH2[(size_t)m * 512 + n] = bfs(v + bias[n]);      // hb16
                    } else {
                        outF2[(size_t)m * 512 + (n - 512)] = v + bias2[n - 512]; // c_state
                    }
                }
            }
}

// ---------------------------------------------------------------------------
// K2: fused e = relu(att1+att2)@att_w + att_b -> softmax -> alpha -> awe.
// ONE block per b, 1024 threads (16 waves). att1 row read once per b.
// Softmax done entirely by wave 0 via shfl_xor butterflies (2 barriers).
// ---------------------------------------------------------------------------
__global__ __launch_bounds__(1024) void att_awe_k(
    const short* __restrict__ att1b, const float* __restrict__ att2b,
    const float* __restrict__ att_w, const float* __restrict__ att_b,
    const short* __restrict__ featb, const float* __restrict__ gatebuf,
    short* __restrict__ xin, float* __restrict__ al_out,
    const int* __restrict__ lens, int t)
{
    const int b = blockIdx.x;
    const int tid = threadIdx.x, lane = tid & 63, wid = tid >> 6;   // 16 waves
    __shared__ float se[224];
    __shared__ float sal[224];

    float aw[8], a2[8];
    #pragma unroll
    for (int j = 0; j < 8; ++j) {
        aw[j] = att_w[lane * 8 + j];
        a2[j] = att2b[b * 512 + lane * 8 + j];
    }
    float ab = att_b[0];
    for (int p = wid; p < Pp; p += 16) {
        s16x8 row = *(const s16x8*)&att1b[((size_t)b * Pp + p) * 512 + lane * 8];
        float s = 0.f;
        #pragma unroll
        for (int j = 0; j < 8; ++j) {
            float v = fbs(row[j]) + a2[j];
            v = v > 0.f ? v : 0.f;
            s += v * aw[j];
        }
        #pragma unroll
        for (int m = 32; m; m >>= 1) s += __shfl_xor(s, m);
        if (lane == 0) se[p] = s + ab;
    }
    __syncthreads();

    // softmax over 196 by wave 0 only (4 values/lane, butterfly reduce)
    if (wid == 0) {
        float v0 = (lane < Pp) ? se[lane] : -3.0e38f;
        float v1 = (lane + 64 < Pp) ? se[lane + 64] : -3.0e38f;
        float v2 = (lane + 128 < Pp) ? se[lane + 128] : -3.0e38f;
        float v3 = (lane + 192 < Pp) ? se[lane + 192] : -3.0e38f;
        float mx = fmaxf(fmaxf(v0, v1), fmaxf(v2, v3));
        #pragma unroll
        for (int m = 32; m; m >>= 1) mx = fmaxf(mx, __shfl_xor(mx, m));
        float e0 = (lane < Pp) ? expf(v0 - mx) : 0.f;
        float e1 = (lane + 64 < Pp) ? expf(v1 - mx) : 0.f;
        float e2 = (lane + 128 < Pp) ? expf(v2 - mx) : 0.f;
        float e3 = (lane + 192 < Pp) ? expf(v3 - mx) : 0.f;
        float sm = e0 + e1 + e2 + e3;
        #pragma unroll
        for (int m = 32; m; m >>= 1) sm += __shfl_xor(sm, m);
        float inv = 1.f / sm;
        float mf = (t < lens[b] - 1) ? 1.f : 0.f;
        float* ao = al_out + ((size_t)b * Tt + t) * Pp;
        if (lane < Pp)       { float a = e0 * inv; sal[lane] = a;       ao[lane] = a * mf; }
        if (lane + 64 < Pp)  { float a = e1 * inv; sal[lane + 64] = a;  ao[lane + 64] = a * mf; }
        if (lane + 128 < Pp) { float a = e2 * inv; sal[lane + 128] = a; ao[lane + 128] = a * mf; }
        if (lane + 192 < Pp) { float a = e3 * inv; sal[lane + 192] = a; ao[lane + 192] = a * mf; }
    }
    __syncthreads();

    // awe: 2 cols per thread over all 2048
    int d0 = tid * 2;
    const short* f = featb + (size_t)b * Pp * Dd + d0;
    float s0 = 0.f, s1 = 0.f;
    #pragma unroll 4
    for (int p = 0; p < Pp; ++p) {
        uint32_t v = *(const uint32_t*)(f + (size_t)p * Dd);
        float lo, hi;
        upk(v, lo, hi);
        float al = sal[p];
        s0 += al * lo;
        s1 += al * hi;
    }
    float2 g = *(const float2*)&gatebuf[b * 2048 + d0];
    uint32_t o = ((uint32_t)(uint16_t)bfs(g.y * s1) << 16) | (uint16_t)bfs(g.x * s0);
    *(uint32_t*)(xin + (size_t)b * 2048 + d0) = o;
}

// ---------------------------------------------------------------------------
// KB: gates = xin(awe) @ combT (quad-perm, K=2048) + hpart + eprec + biases
//     -> LSTM update. grid 256: m0=(bid&3)*32, n0=(bid>>2)*32.
// Pipelined k-loop: 2x-unrolled register double-buffer.
// ---------------------------------------------------------------------------
__global__ __launch_bounds__(256) void gates_lstm_k(
    const short* __restrict__ xin, const short* __restrict__ combT,
    const short* __restrict__ eprec, const float* __restrict__ hpart,
    const float* __restrict__ b_ih, const float* __restrict__ b_hh,
    float* __restrict__ c_state, short* __restrict__ hnew_all,
    short* __restrict__ hb16, const int* __restrict__ lens, int t)
{
    constexpr int BM = 32, BN = 32, BK = 128, K = 2048;  // 2048 = 16 * 128
    constexpr int NCH = BK / 8;                          // 16
    constexpr int AU = NCH * BM;                         // 512 16B-units
    __shared__ __align__(16) short sA[AU * 8];
    __shared__ __align__(16) short sB[AU * 8];

    const int m0 = ((int)blockIdx.x & 3) * BM, n0 = ((int)blockIdx.x >> 2) * BN;
    const int tid = threadIdx.x, lane = tid & 63, wid = tid >> 6;
    const int l15 = lane & 15, l4 = lane >> 4;
    const int wr = wid >> 1, wc = wid & 1;               // WR=2, WC=2

    f32x4 acc = {0.f, 0.f, 0.f, 0.f};
    const int r2 = tid / NCH, ch0 = tid % NCH;           // rows r2, r2+16
    const short* Abase = xin + (size_t)(m0 + r2) * 2048 + ch0 * 8;
    const short* Bbase = combT + (size_t)(n0 + r2) * 2048 + ch0 * 8;
    const size_t rowadv = (size_t)16 * 2048;

    s16x8 raA0, raA1, rbA0, rbA1, raB0, raB1, rbB0, rbB1;

    auto loadA = [&](int kt, s16x8& a0, s16x8& a1, s16x8& b0, s16x8& b1) {
        a0 = *(const s16x8*)(Abase + kt);
        a1 = *(const s16x8*)(Abase + rowadv + kt);
        b0 = *(const s16x8*)(Bbase + kt);
        b1 = *(const s16x8*)(Bbase + rowadv + kt);
    };
    const int sl0 = ((r2) * NCH + (ch0 ^ (r2 & 7))) * 8;
    const int sl1 = ((r2 + 16) * NCH + (ch0 ^ ((r2 + 16) & 7))) * 8;
    auto storeS = [&](s16x8& a0, s16x8& a1, s16x8& b0, s16x8& b1) {
        *(s16x8*)(sA + sl0) = a0;
        *(s16x8*)(sA + sl1) = a1;
        *(s16x8*)(sB + sl0) = b0;
        *(s16x8*)(sB + sl1) = b1;
    };
    const int rrA = wr * 16 + l15, rrB = wc * 16 + l15;
    auto mfmaS = [&]() {
        #pragma unroll
        for (int ks = 0; ks < BK / 32; ++ks) {
            int cc = ks * 4 + l4;
            s16x8 af = *(const s16x8*)&sA[(rrA * NCH + (cc ^ (rrA & 7))) * 8];
            s16x8 bf = *(const s16x8*)&sB[(rrB * NCH + (cc ^ (rrB & 7))) * 8];
            acc = __builtin_amdgcn_mfma_f32_16x16x32_bf16(af, bf, acc, 0, 0, 0);
        }
    };

    loadA(0, raA0, raA1, rbA0, rbA1);
    #pragma unroll 1
    for (int kt = 0; kt < K; kt += 2 * BK) {
        __syncthreads();
        storeS(raA0, raA1, rbA0, rbA1);
        __syncthreads();
        if (kt + BK < K) loadA(kt + BK, raB0, raB1, rbB0, rbB1);
        mfmaS();
        __syncthreads();
        storeS(raB0, raB1, rbB0, rbB1);
        __syncthreads();
        if (kt + 2 * BK < K) loadA(kt + 2 * BK, raA0, raA1, rbA0, rbA1);
        mfmaS();
    }

    // LSTM epilogue via LDS round-trip (quad-permuted cols: q = n0/4 + jl)
    __syncthreads();
    float* sE = (float*)sA;
    #pragma unroll
    for (int r = 0; r < 4; ++r) {
        int ml = wr * 16 + l4 * 4 + r, nl = wc * 16 + l15;
        sE[ml * 32 + nl] = acc[r];
    }
    __syncthreads();
    int bl = tid >> 3, jl = tid & 7;
    int b = m0 + bl, q = (n0 >> 2) + jl;
    f32x4 ge = *(const f32x4*)&sE[bl * 32 + jl * 4];
    f32x4 hp = *(const f32x4*)&hpart[(size_t)b * 2048 + n0 + jl * 4];
    short4 ep = *(const short4*)&eprec[((size_t)t * 128 + b) * 2048 + n0 + jl * 4];
    float gi = ge[0] + hp[0] + fbs(ep.x) + b_ih[q]        + b_hh[q];
    float gf = ge[1] + hp[1] + fbs(ep.y) + b_ih[512 + q]  + b_hh[512 + q];
    float gg = ge[2] + hp[2] + fbs(ep.z) + b_ih[1024 + q] + b_hh[1024 + q];
    float go = ge[3] + hp[3] + fbs(ep.w) + b_ih[1536 + q] + b_hh[1536 + q];
    float si = 1.f / (1.f + expf(-gi));
    float sf = 1.f / (1.f + expf(-gf));
    float so = 1.f / (1.f + expf(-go));
    float tg = tanhf(gg);
    int sidx = b * 512 + q;
    float cn = sf * c_state[sidx] + si * tg;
    float hn = so * tanhf(cn);
    hnew_all[((size_t)t * 128 + b) * 512 + q] = bfs(hn);
    if (t < lens[b] - 1) {
        c_state[sidx] = cn;
        hb16[sidx] = bfs(hn);
    }
}

// ---------------------------------------------------------------------------
// conv/mean: features fp32 -> bf16, bf16 mean over P.  grid (4,128), 2 d/thr.
// ---------------------------------------------------------------------------
__global__ __launch_bounds__(256) void conv_mean_k(
    const float* __restrict__ feat, short* __restrict__ featb, short* __restrict__ meanb)
{
    int b = blockIdx.y;
    int d = (blockIdx.x * 256 + threadIdx.x) * 2;
    const float* f = feat + (size_t)b * Pp * Dd + d;
    short* o = featb + (size_t)b * Pp * Dd + d;
    float s0 = 0.f, s1 = 0.f;
    #pragma unroll 4
    for (int p = 0; p < Pp; ++p) {
        float2 v = *(const float2*)(f + (size_t)p * Dd);
        s0 += v.x; s1 += v.y;
        uint32_t ov = ((uint32_t)(uint16_t)bfs(v.y) << 16) | (uint16_t)bfs(v.x);
        *(uint32_t*)(o + (size_t)p * Dd) = ov;
    }
    const float inv = 1.f / 196.f;
    uint32_t mv = ((uint32_t)(uint16_t)bfs(s1 * inv) << 16) | (uint16_t)bfs(s0 * inv);
    *(uint32_t*)(meanb + (size_t)b * Dd + d) = mv;
}

// ---------------------------------------------------------------------------
// prep_k: weight transposes + embedding gather in ONE launch.
// Section boundaries (ABSOLUTE block ids; grid MUST be 20416):
//   [0,1024) enc | [1024,2048) h_fc | [2048,3072) c_fc | [3072,3328) dec
//   [3328,4352) beta | [4352,5376) w_hh-qp | [5376,9472) w_ih-bot
//   [9472,10496) w_ih-top | [10496,15552) cls (gx=316) | [15552,20416) embg
// ---------------------------------------------------------------------------
DEV void t32(const float* __restrict__ src, int R, int C,
             short* __restrict__ dst, int ds, int off, int perm,
             int local, int gx, float (*tile)[33])
{
    int x = local % gx, y = local / gx;
    int c0 = x * 32, r0 = y * 32;
    int tx = threadIdx.x & 31, ty = threadIdx.x >> 5;
    #pragma unroll
    for (int i = 0; i < 4; ++i) {
        int r = r0 + ty + i * 8, c = c0 + tx;
        tile[ty + i * 8][tx] = (r < R && c < C) ? src[(size_t)r * C + c] : 0.f;
    }
    __syncthreads();
    #pragma unroll
    for (int i = 0; i < 4; ++i) {
        int cc = c0 + ty + i * 8, rr = r0 + tx;
        if (rr < R) {
            int drow = perm ? ((cc & 511) * 4 + (cc >> 9)) : cc;
            dst[(size_t)drow * ds + off + rr] = bfs(tile[tx][ty + i * 8]);
        }
    }
}

__global__ __launch_bounds__(256) void prep_k(
    const float* __restrict__ enc_w, const float* __restrict__ h_fc_w,
    const float* __restrict__ c_fc_w, const float* __restrict__ dec_w,
    const float* __restrict__ beta_w, const float* __restrict__ w_ih,
    const float* __restrict__ w_hh, const float* __restrict__ cls_w,
    const float* __restrict__ emb, const int* __restrict__ caps,
    short* __restrict__ encT, short* __restrict__ hcT, short* __restrict__ catT,
    short* __restrict__ combT, short* __restrict__ wtopT, short* __restrict__ clsT,
    short* __restrict__ embseq)
{
    __shared__ float tile[32][33];
    int bid = blockIdx.x;
    if (bid < 1024)        t32(enc_w, 2048, 512, encT, 2048, 0, 0, bid, 16, tile);
    else if (bid < 2048)   t32(h_fc_w, 2048, 512, hcT, 2048, 0, 0, bid - 1024, 16, tile);
    else if (bid < 3072)   t32(c_fc_w, 2048, 512, hcT + (size_t)512 * 2048, 2048, 0, 0, bid - 2048, 16, tile);
    else if (bid < 3328)   t32(dec_w, 512, 512, catT, 512, 0, 0, bid - 3072, 16, tile);
    else if (bid < 4352)   t32(beta_w, 512, 2048, catT + (size_t)512 * 512, 512, 0, 0, bid - 3328, 64, tile);
    else if (bid < 5376)   t32(w_hh, 512, 2048, catT + (size_t)2560 * 512, 512, 0, 1, bid - 4352, 64, tile);
    else if (bid < 9472)   t32(w_ih + (size_t)512 * 2048, 2048, 2048, combT, 2048, 0, 1, bid - 5376, 64, tile);
    else if (bid < 10496)  t32(w_ih, 512, 2048, wtopT, 512, 0, 1, bid - 9472, 64, tile);
    else if (bid < 15552)  t32(cls_w, 512, 10000, clsT, 512, 0, 0, bid - 10496, 316, tile);
    else {
        size_t i = (size_t)(bid - 15552) * 256 + threadIdx.x;
        if (i < (size_t)Tt * Bb * Ee) {
            int e = (int)(i % Ee);
            size_t r = i / Ee;
            int b = (int)(r % Bb);
            int t = (int)(r / Bb);
            int cap = caps[b * TMAX + t];
            embseq[i] = bfs(emb[(size_t)cap * Ee + e]);
        }
    }
}

// ---------------------------------------------------------------------------
extern "C" void kernel_launch(void* const* d_in, const int* in_sizes, int n_in,
                              void* d_out, int out_size, void* d_ws, size_t ws_size,
                              hipStream_t stream)
{
    const float* features = (const float*)d_in[0];
    const int* captions   = (const int*)d_in[1];
    const int* lengths    = (const int*)d_in[2];
    const float* emb      = (const float*)d_in[3];
    const float* h_fc_w   = (const float*)d_in[4];
    const float* h_fc_b   = (const float*)d_in[5];
    const float* c_fc_w   = (const float*)d_in[6];
    const float* c_fc_b   = (const float*)d_in[7];
    const float* enc_w    = (const float*)d_in[8];
    const float* enc_b    = (const float*)d_in[9];
    const float* dec_w    = (const float*)d_in[10];
    const float* dec_b    = (const float*)d_in[11];
    const float* att_w    = (const float*)d_in[12];
    const float* att_b    = (const float*)d_in[13];
    const float* beta_w   = (const float*)d_in[14];
    const float* beta_b   = (const float*)d_in[15];
    const float* w_ih     = (const float*)d_in[16];
    const float* b_ih     = (const float*)d_in[17];
    const float* w_hh     = (const float*)d_in[18];
    const float* b_hh     = (const float*)d_in[19];
    const float* cls_w    = (const float*)d_in[20];
    const float* cls_b    = (const float*)d_in[21];

    char* w = (char*)d_ws;
    auto alloc = [&](size_t bytes) {
        char* p = w;
        w += (bytes + 255) & ~(size_t)255;
        return p;
    };
    short* featb    = (short*)alloc((size_t)Bb * Pp * Dd * 2);
    short* att1b    = (short*)alloc((size_t)Bb * Pp * Aa * 2);
    short* encT     = (short*)alloc((size_t)Aa * Dd * 2);
    short* combT    = (short*)alloc((size_t)2048 * 2048 * 2); // w_ih bottom, qp rows
    short* wtopT    = (short*)alloc((size_t)2048 * 512 * 2);  // w_ih top, qp rows
    short* clsT     = (short*)alloc((size_t)NVP * Hh * 2);
    short* catT     = (short*)alloc((size_t)4608 * 512 * 2);  // [dec|beta|whh-qp]
    short* hcT      = (short*)alloc((size_t)1024 * Dd * 2);   // [h_fc;c_fc]
    short* embseq   = (short*)alloc((size_t)Tt * Bb * Ee * 2);
    short* meanb    = (short*)alloc((size_t)Bb * Dd * 2);
    short* eprec    = (short*)alloc((size_t)Tt * Bb * 2048 * 2);
    float* c_state  = (float*)alloc((size_t)Bb * Hh * 4);
    float* att2b    = (float*)alloc((size_t)Bb * Aa * 4);
    float* gatebuf  = (float*)alloc((size_t)Bb * Dd * 4);
    float* hpart    = (float*)alloc((size_t)Bb * 2048 * 4);
    short* xin      = (short*)alloc((size_t)Bb * 2048 * 2);   // awe only
    short* hb16     = (short*)alloc((size_t)Bb * Hh * 2);
    short* hnew_all = (short*)alloc((size_t)Tt * Bb * Hh * 2);

    float* y_out  = (float*)d_out;
    float* al_out = y_out + (size_t)Bb * Tt * Vv;

    // ---- precompute (5 launches) ----
    conv_mean_k<<<dim3(4, 128), 256, 0, stream>>>(features, featb, meanb);
    prep_k<<<dim3(20416), 256, 0, stream>>>(
        enc_w, h_fc_w, c_fc_w, dec_w, beta_w, w_ih, w_hh, cls_w, emb, captions,
        encT, hcT, catT, combT, wtopT, clsT, embseq);

    // h0/c0 GEMM: meanb @ hcT^T (EPI 6) -> hb16 + c_state
    gemm_k<128, 64, 64, 256, 2, 2, 6><<<dim3(16, 1), 256, 0, stream>>>(
        meanb, 2048, hcT, 2048, 2048,
        nullptr, c_state, nullptr, hb16, 0, h_fc_b, c_fc_b, nullptr);

    // att1 = features @ enc_w + enc_b (bf16), XCD-chunked 392-block grid
    gemm_k<128, 256, 64, 512, 2, 4, 0><<<dim3(392), 512, 0, stream>>>(
        featb, 2048, encT, 2048, 2048,
        nullptr, nullptr, att1b, nullptr, Aa, enc_b, nullptr, nullptr);

    // eprec = embseq @ wtopT^T (bf16, quad-permuted cols), all 19 steps
    gemm_k<128, 64, 64, 256, 2, 2, 1><<<dim3(32, 19), 256, 0, stream>>>(
        embseq, 512, wtopT, 512, 512,
        nullptr, nullptr, eprec, nullptr, 2048, nullptr, nullptr, nullptr);

    // ---- decode steps: 3 launches each ----
    for (int t = 0; t < Tt; ++t) {
        // K1: h @ [dec|beta|whh-qp], N=4608, K=512, BK=128, 288 blocks
        gemm_k<32, 64, 128, 256, 2, 2, 4><<<dim3(288), 256, 0, stream>>>(
            hb16, 512, catT, 512, 512,
            att2b, gatebuf, (short*)hpart, nullptr, 0, dec_b, beta_b, nullptr);
        // K2: fused e/softmax/awe -> xin (+alpha output), 1 block/b
        att_awe_k<<<dim3(128), 1024, 0, stream>>>(
            att1b, att2b, att_w, att_b, featb, gatebuf, xin,
            al_out, lengths, t);
        // KB: gates GEMM (K=2048) + hpart + eprec + LSTM
        gates_lstm_k<<<dim3(256), 256, 0, stream>>>(
            xin, combT, eprec, hpart, b_ih, b_hh, c_state, hnew_all, hb16,
            lengths, t);
    }

    // deferred y: hnew_all[2432][512] @ clsT^T (128x128 tiles), XCD-chunked
    gemm_k<128, 128, 64, 256, 2, 2, 3><<<dim3(79 * Tt), 256, 0, stream>>>(
        hnew_all, 512, clsT, 512, 512,
        y_out, nullptr, nullptr, nullptr, 0, cls_b, nullptr, lengths);
}